// Round 3
// baseline (1410.020 us; speedup 1.0000x reference)
//
#include <hip/hip_runtime.h>
#include <cstdint>

typedef unsigned short ushort_t;
typedef __attribute__((ext_vector_type(8))) short short8;   // 8 bf16 in 4 VGPRs (guide §3)
typedef __attribute__((ext_vector_type(4))) float floatx4;

#define HID    5120
#define NHEAD  16
#define NOPE   128
#define ROPE_D 64
#define VDIM   128
#define QHD    192
#define QLORA  1536
#define KVLORA 512
#define SEQ    2048
#define PAST   2048
#define TOTK   4096
#define EPS_RMS 1e-6f
#define SCALE_DEV 0.125f
#define LOG2E 1.4426950408889634f
#define ATT_SCALE 0.07216878364870322f   /* 1/sqrt(192) */
#define LOG2_10000 13.287712379549449f

__device__ __forceinline__ float bf2f(ushort_t u) {
  unsigned int x = ((unsigned int)u) << 16;
  return __builtin_bit_cast(float, x);
}
__device__ __forceinline__ ushort_t f2bf(float f) {
  unsigned int u = __builtin_bit_cast(unsigned int, f);
  unsigned int r = u + 0x7fffu + ((u >> 16) & 1u);   // RNE
  return (ushort_t)(r >> 16);
}
__device__ __forceinline__ void unpack8(uint4 c, float* f) {
  const ushort_t* p = (const ushort_t*)&c;
#pragma unroll
  for (int i = 0; i < 8; ++i) f[i] = bf2f(p[i]);
}
__device__ __forceinline__ uint4 pack8(const float* f) {
  uint4 c;
  ushort_t* p = (ushort_t*)&c;
#pragma unroll
  for (int i = 0; i < 8; ++i) p[i] = f2bf(f[i]);
  return c;
}

// fp32 -> bf16 bulk convert, 8 elems/thread, exact grid (n % 8 == 0)
__global__ void cvt_kernel(const float* __restrict__ src, ushort_t* __restrict__ dst)
{
  long i = ((long)blockIdx.x * 256 + threadIdx.x) * 8;
  float f[8];
  *(float4*)(f)     = *(const float4*)(src + i);
  *(float4*)(f + 4) = *(const float4*)(src + i + 4);
  *(uint4*)(dst + i) = pack8(f);
}

// ---------------------------------------------------------------------------
// GEMM: C(MxN) = A(MxK,bf16,row-major) @ B(NxK,bf16,row-major)^T
// R0 structure (best measured on these skinny grids): 128x128 tile, BK=32,
// 4 waves x (64x64 via 4x4 16x16x32 MFMAs). LDS rows padded +8 bf16 (stride
// 40): fragment ds_read_b128 is 2-way (free). VGPR software prefetch of next
// K-slab. M%128==0, K%32==0; N guarded.
// ---------------------------------------------------------------------------
#define GLDT 40
__global__ __launch_bounds__(256, 2) void gemm_bt(
    const ushort_t* __restrict__ A, const ushort_t* __restrict__ B,
    ushort_t* __restrict__ Cb, float* __restrict__ Cf,
    const float* __restrict__ resid, float resid_scale,
    int M, int N, int K)
{
  __shared__ __align__(16) ushort_t As[128 * GLDT];
  __shared__ __align__(16) ushort_t Bs[128 * GLDT];
  int t = threadIdx.x;
  int lane = t & 63, wave = t >> 6;
  int wm = wave >> 1, wn = wave & 1;
  int lrow = lane & 15, quad = lane >> 4;
  long bm = (long)blockIdx.y * 128;
  long bn = (long)blockIdx.x * 128;

  int r0 = t >> 2, cc = t & 3;       // chunk 0: rows 0..63
  int r1 = r0 + 64;                  // chunk 1: rows 64..127
  const ushort_t* a0 = A + (bm + r0) * (long)K + cc * 8;
  const ushort_t* a1 = A + (bm + r1) * (long)K + cc * 8;
  long nb0 = bn + r0; if (nb0 > N - 1) nb0 = N - 1;
  long nb1 = bn + r1; if (nb1 > N - 1) nb1 = N - 1;
  const ushort_t* b0 = B + nb0 * (long)K + cc * 8;
  const ushort_t* b1 = B + nb1 * (long)K + cc * 8;

  floatx4 acc[4][4];
#pragma unroll
  for (int i = 0; i < 4; ++i)
#pragma unroll
    for (int j = 0; j < 4; ++j) acc[i][j] = (floatx4)0.f;

  uint4 pa0 = *(const uint4*)a0;
  uint4 pa1 = *(const uint4*)a1;
  uint4 pb0 = *(const uint4*)b0;
  uint4 pb1 = *(const uint4*)b1;

  int nk = K >> 5;
  for (int kt = 0; kt < nk; ++kt) {
    *(uint4*)&As[r0 * GLDT + cc * 8] = pa0;
    *(uint4*)&As[r1 * GLDT + cc * 8] = pa1;
    *(uint4*)&Bs[r0 * GLDT + cc * 8] = pb0;
    *(uint4*)&Bs[r1 * GLDT + cc * 8] = pb1;
    __syncthreads();
    if (kt + 1 < nk) {
      int off = (kt + 1) << 5;
      pa0 = *(const uint4*)(a0 + off);
      pa1 = *(const uint4*)(a1 + off);
      pb0 = *(const uint4*)(b0 + off);
      pb1 = *(const uint4*)(b1 + off);
    }
    short8 af[4], bfr[4];
#pragma unroll
    for (int mt = 0; mt < 4; ++mt)
      af[mt] = *(const short8*)&As[(wm * 64 + mt * 16 + lrow) * GLDT + quad * 8];
#pragma unroll
    for (int nt = 0; nt < 4; ++nt)
      bfr[nt] = *(const short8*)&Bs[(wn * 64 + nt * 16 + lrow) * GLDT + quad * 8];
#pragma unroll
    for (int mt = 0; mt < 4; ++mt)
#pragma unroll
      for (int nt = 0; nt < 4; ++nt)
        acc[mt][nt] = __builtin_amdgcn_mfma_f32_16x16x32_bf16(af[mt], bfr[nt], acc[mt][nt], 0, 0, 0);
    __syncthreads();
  }

  // epilogue: D layout col=lane&15, row=quad*4+reg (guide §3, m89-verified)
#pragma unroll
  for (int mt = 0; mt < 4; ++mt) {
    long grow = bm + wm * 64 + mt * 16 + quad * 4;
#pragma unroll
    for (int nt = 0; nt < 4; ++nt) {
      long gcol = bn + wn * 64 + nt * 16 + lrow;
      if (gcol < N) {
#pragma unroll
        for (int r2 = 0; r2 < 4; ++r2) {
          long row = grow + r2;
          float v = acc[mt][nt][r2];
          if (Cf) {
            if (resid) v += resid_scale * resid[row * (long)N + gcol];
            Cf[row * (long)N + gcol] = v;
          } else {
            Cb[row * (long)N + gcol] = f2bf(v);
          }
        }
      }
    }
  }
}

// ---------------------------------------------------------------------------
// RMSNorm kernels (fp32 inputs where they come from d_in)
// ---------------------------------------------------------------------------
__global__ void rms_in_kernel(const float* __restrict__ x,
                              const float* __restrict__ w,
                              ushort_t* __restrict__ out)
{
  int row = blockIdx.x, t = threadIdx.x;  // 320 threads, 16 elems each
  const float* xr = x + (long)row * HID + t * 16;
  float v[16];
#pragma unroll
  for (int i = 0; i < 4; ++i) *(float4*)(v + i * 4) = *(const float4*)(xr + i * 4);
  float ss = 0.f;
#pragma unroll
  for (int i = 0; i < 16; ++i) ss += v[i] * v[i];
#pragma unroll
  for (int o = 1; o < 64; o <<= 1) ss += __shfl_xor(ss, o);
  __shared__ float red[5];
  if ((t & 63) == 0) red[t >> 6] = ss;
  __syncthreads();
  float tot = red[0] + red[1] + red[2] + red[3] + red[4];
  float sc = rsqrtf(tot / (float)HID + EPS_RMS);
  float wv[16];
#pragma unroll
  for (int i = 0; i < 4; ++i) *(float4*)(wv + i * 4) = *(const float4*)(w + t * 16 + i * 4);
#pragma unroll
  for (int i = 0; i < 16; ++i) v[i] *= sc * wv[i];
  ushort_t* o = out + (long)row * HID + t * 16;
  *(uint4*)o       = pack8(v);
  *(uint4*)(o + 8) = pack8(v + 8);
}

__global__ void rms_qa_kernel(const ushort_t* __restrict__ x,
                              const float* __restrict__ w,
                              ushort_t* __restrict__ out)
{
  int row = blockIdx.x, t = threadIdx.x;  // 192 threads, 8 elems each
  const ushort_t* xr = x + (long)row * QLORA;
  float v[8];
  unpack8(*(const uint4*)(xr + t * 8), v);
  float ss = 0.f;
#pragma unroll
  for (int i = 0; i < 8; ++i) ss += v[i] * v[i];
#pragma unroll
  for (int o = 1; o < 64; o <<= 1) ss += __shfl_xor(ss, o);
  __shared__ float red[3];
  if ((t & 63) == 0) red[t >> 6] = ss;
  __syncthreads();
  float tot = red[0] + red[1] + red[2];
  float sc = rsqrtf(tot / (float)QLORA + EPS_RMS);
  float wv[8];
  *(float4*)(wv)     = *(const float4*)(w + t * 8);
  *(float4*)(wv + 4) = *(const float4*)(w + t * 8 + 4);
#pragma unroll
  for (int i = 0; i < 8; ++i) v[i] *= sc * wv[i];
  *(uint4*)(out + (long)row * QLORA + t * 8) = pack8(v);
}

// rmsnorm first 512 of ckv row (bf16 in); rope last 64 (k_pe):
// write bf16 ckv_n + bf16 kpe + fp32 k_out rope dims for all heads
__global__ void rms_ckv_rope(const ushort_t* __restrict__ ckv_raw,
                             const float* __restrict__ w,
                             const int* __restrict__ pos_ids,
                             ushort_t* __restrict__ ckv_n,
                             ushort_t* __restrict__ kpe,
                             float* __restrict__ k_out)
{
  int row = blockIdx.x, t = threadIdx.x;  // 64 threads (1 wave)
  const ushort_t* xr = ckv_raw + (long)row * 576;
  float v[8];
  unpack8(*(const uint4*)(xr + t * 8), v);
  float ss = 0.f;
#pragma unroll
  for (int i = 0; i < 8; ++i) ss += v[i] * v[i];
#pragma unroll
  for (int o = 1; o < 64; o <<= 1) ss += __shfl_xor(ss, o);
  float sc = rsqrtf(ss / (float)KVLORA + EPS_RMS);
  float wv[8];
  *(float4*)(wv)     = *(const float4*)(w + t * 8);
  *(float4*)(wv + 4) = *(const float4*)(w + t * 8 + 4);
  float ov[8];
#pragma unroll
  for (int i = 0; i < 8; ++i) ov[i] = v[i] * sc * wv[i];
  *(uint4*)(ckv_n + (long)row * KVLORA + t * 8) = pack8(ov);

  if (t < 32) {
    float e  = bf2f(xr[512 + 2 * t]);
    float od = bf2f(xr[512 + 2 * t + 1]);
    float p = (float)pos_ids[row];
    float inv = __builtin_exp2f(-((float)t / 32.f) * LOG2_10000);
    float ang = p * inv, sn, cs;
    sincosf(ang, &sn, &cs);
    float r1 = e * cs - od * sn;
    float r2 = od * cs + e * sn;
    kpe[(long)row * 64 + t]      = f2bf(r1);
    kpe[(long)row * 64 + 32 + t] = f2bf(r2);
#pragma unroll
    for (int h = 0; h < NHEAD; ++h) {
      float* kr = k_out + ((long)h * TOTK + PAST + row) * QHD + NOPE;
      kr[t] = r1;
      kr[32 + t] = r2;
    }
  }
}

// q post: scale nope by ATT_SCALE; rope+scale pe. q_raw/q_bf layout (s, 16, 192)
__global__ void qpost_kernel(const ushort_t* __restrict__ q_raw,
                             const int* __restrict__ pos_ids,
                             ushort_t* __restrict__ q_bf)
{
  int row = blockIdx.x, t = threadIdx.x;  // 256
  const ushort_t* qr = q_raw + (long)row * 3072;
  ushort_t* qo = q_bf + (long)row * 3072;
  {
    int hh = t >> 4, c = t & 15;
    float v[8];
    unpack8(*(const uint4*)(qr + hh * QHD + c * 8), v);
#pragma unroll
    for (int i = 0; i < 8; ++i) v[i] *= ATT_SCALE;
    *(uint4*)(qo + hh * QHD + c * 8) = pack8(v);
  }
  float p = (float)pos_ids[row];
#pragma unroll
  for (int it = 0; it < 2; ++it) {
    int slot = t + it * 256;
    int hh = slot >> 5, i = slot & 31;
    float e  = bf2f(qr[hh * QHD + NOPE + 2 * i]);
    float od = bf2f(qr[hh * QHD + NOPE + 2 * i + 1]);
    float inv = __builtin_exp2f(-((float)i / 32.f) * LOG2_10000);
    float ang = p * inv, sn, cs;
    sincosf(ang, &sn, &cs);
    qo[hh * QHD + NOPE + i]      = f2bf((e * cs - od * sn) * ATT_SCALE);
    qo[hh * QHD + NOPE + 32 + i] = f2bf((od * cs + e * sn) * ATT_SCALE);
  }
}

// kv post: split kv_raw (s, h*256 + [nope128|v128]) bf16 into fp32 k_out/v_out new rows
__global__ void kvpost_kernel(const ushort_t* __restrict__ kv_raw,
                              float* __restrict__ k_out,
                              float* __restrict__ v_out)
{
  int row = blockIdx.x, t = threadIdx.x;
  const ushort_t* kr = kv_raw + (long)row * 4096;
#pragma unroll
  for (int it = 0; it < 2; ++it) {
    int c = t + it * 256;
    int hh = c >> 5, cc = c & 31;
    float v[8];
    unpack8(*(const uint4*)(kr + c * 8), v);
    float* dst;
    if (cc < 16) dst = k_out + ((long)hh * TOTK + PAST + row) * QHD + cc * 8;
    else         dst = v_out + ((long)hh * TOTK + PAST + row) * VDIM + (cc - 16) * 8;
    floatx4 f0 = {v[0], v[1], v[2], v[3]};
    floatx4 f1 = {v[4], v[5], v[6], v[7]};
    *(floatx4*)dst = f0;
    *(floatx4*)(dst + 4) = f1;
  }
}

// past_k/past_v (fp32) -> fp32 k_out/v_out rows [0, PAST): strided copy, float4
__global__ void past_kernel(const float* __restrict__ past_k,
                            const float* __restrict__ past_v,
                            float* __restrict__ k_out,
                            float* __restrict__ v_out)
{
  long c = (long)blockIdx.x * 256 + threadIdx.x;  // chunk of 4 floats
  if (c < 1572864) {  // k: 16*2048*48 chunks
    float4 v = *(const float4*)(past_k + c * 4);
    long hh = c / 98304, rem = c % 98304;      // 2048*48 per head
    long s = rem / 48, cc = rem % 48;
    *(float4*)(k_out + (hh * (long)TOTK + s) * QHD + cc * 4) = v;
  } else {
    long c2 = c - 1572864;  // v: 16*2048*32 chunks
    float4 v = *(const float4*)(past_v + c2 * 4);
    long hh = c2 / 65536, rem = c2 % 65536;
    long s = rem / 32, cc = rem % 32;
    *(float4*)(v_out + (hh * (long)TOTK + s) * VDIM + cc * 4) = v;
  }
}

// Build attention-tiled bf16 K: granule g = ((h*64+kt)*24 + cc)*64 + ko (16B granules)
__global__ void buildK_kernel(const float* __restrict__ past_k,
                              const ushort_t* __restrict__ kv_raw,
                              const ushort_t* __restrict__ kpe,
                              ushort_t* __restrict__ Kc)
{
  long g = (long)blockIdx.x * 256 + threadIdx.x;  // < 1,572,864
  int ko = (int)(g & 63);
  long r = g >> 6;
  int cc = (int)(r % 24);
  long r2 = r / 24;
  int kt = (int)(r2 & 63);
  int hh = (int)(r2 >> 6);
  int key = kt * 64 + ko;
  uint4 val;
  if (key < PAST) {
    const float* src = past_k + ((long)hh * PAST + key) * QHD + cc * 8;
    float f[8];
    *(float4*)(f)     = *(const float4*)src;
    *(float4*)(f + 4) = *(const float4*)(src + 4);
    val = pack8(f);
  } else {
    int s = key - PAST;
    int d0 = cc * 8;
    if (d0 < NOPE) val = *(const uint4*)(kv_raw + (long)s * 4096 + hh * 256 + d0);
    else           val = *(const uint4*)(kpe + (long)s * 64 + (d0 - NOPE));
  }
  *(uint4*)(Kc + g * 8) = val;
}

// Build attention-tiled bf16 V^T: granule gv = ((h*64+kt)*128 + vd)*8 + kchunk
// (dense stride 8; no LDS pad needed -- attn reads V direct from L2)
__global__ void buildV_kernel(const float* __restrict__ past_v,
                              const ushort_t* __restrict__ kv_raw,
                              ushort_t* __restrict__ Vc)
{
  long tid = (long)blockIdx.x * 256 + threadIdx.x;  // < 1,048,576
  int vd = (int)(tid & 127);
  long r = tid >> 7;
  int kchunk = (int)(r & 7);
  long r2 = r >> 3;
  int kt = (int)(r2 & 63);
  int hh = (int)(r2 >> 6);
  int key0 = kt * 64 + kchunk * 8;
  __align__(16) ushort_t tmp[8];
  if (key0 < PAST) {
#pragma unroll
    for (int j = 0; j < 8; ++j)
      tmp[j] = f2bf(past_v[((long)hh * PAST + key0 + j) * VDIM + vd]);
  } else {
    int s = key0 - PAST;
#pragma unroll
    for (int j = 0; j < 8; ++j)
      tmp[j] = kv_raw[(long)(s + j) * 4096 + hh * 256 + NOPE + vd];
  }
  *(uint4*)(Vc + ((((long)hh * 64 + kt) * 128 + vd) * 8 + kchunk) * 8) = *(uint4*)tmp;
}

// ---------------------------------------------------------------------------
// Flash attention: one block = (head, 64 q-rows). 4 waves x 16 q-rows each.
// Round-3 structure (guide Common-mistake #7, m169: don't LDS-stage what
// L2-fits): with the XCD head swizzle, each XCD's K+V working set is one
// head = 2.5MB < 4MB L2. So NO K/V LDS staging -- MFMA B-operand fragments
// are read directly from the tiled Kc/Vc global buffers (each fragment is a
// contiguous aligned 16B granule). This deletes all staging loads/ds_writes
// and EVERY __syncthreads in the loop: waves free-run, hiding each other's
// QK->softmax->PV serial chains. P roundtrip stays wave-private LDS (compiler
// inserts the wave-local lgkmcnt hazard wait; LDS = 9KB total).
// ---------------------------------------------------------------------------
__global__ __launch_bounds__(256, 2) void attn_kernel(
    const ushort_t* __restrict__ qb,        // (s,16,192) bf16, pre-scaled
    const ushort_t* __restrict__ Kc,        // tiled bf16 K
    const ushort_t* __restrict__ Vc,        // tiled bf16 V^T (dense, stride 8)
    const float* __restrict__ attn_mask,    // (2048,4096) fp32
    ushort_t* __restrict__ ctx)             // (2048, 2048) bf16
{
  __shared__ __align__(16) ushort_t Pl[4 * 16 * 72];

  int t = threadIdx.x, lane = t & 63, wave = t >> 6;
  int lrow = lane & 15, quad = lane >> 4;
  // XCD swizzle: dispatch order = linear id; id%8 = XCD (8 XCDs, m09).
  int lb = blockIdx.y * 32 + blockIdx.x;          // [0, 512)
  int xcd = lb & 7, j = lb >> 3;                  // j in [0, 64)
  int h = xcd + 8 * (j >> 5);                     // each XCD: head xcd, then xcd+8
  int q0 = (j & 31) * 64;
  int qrow_a = q0 + wave * 16 + lrow;
  int qrow_c = q0 + wave * 16 + quad * 4;

  short8 aq[6];
  const ushort_t* qp = qb + ((long)qrow_a * 16 + h) * QHD + quad * 8;
#pragma unroll
  for (int kc = 0; kc < 6; ++kc) aq[kc] = *(const short8*)(qp + kc * 32);

  float m_r[4], l_r[4];
  floatx4 cacc[8];
#pragma unroll
  for (int r = 0; r < 4; ++r) { m_r[r] = -1e30f; l_r[r] = 0.f; }
#pragma unroll
  for (int v = 0; v < 8; ++v) cacc[v] = (floatx4)0.f;

  const ushort_t* Kbase = Kc + (long)h * 64 * 1536 * 8;   // 1536 granules/tile
  const ushort_t* Vbase = Vc + (long)h * 64 * 1024 * 8;   // 1024 granules/tile

  for (int kt2 = 0; kt2 < 64; ++kt2) {
    const ushort_t* ks = Kbase + (long)kt2 * 1536 * 8;

    // S = q . k  (scale pre-folded into q); K fragments straight from L2
    floatx4 sacc[4];
#pragma unroll
    for (int nt = 0; nt < 4; ++nt) sacc[nt] = (floatx4)0.f;
#pragma unroll
    for (int kc = 0; kc < 6; ++kc) {
#pragma unroll
      for (int nt = 0; nt < 4; ++nt) {
        short8 bk = *(const short8*)(ks + (((kc * 4 + quad) * 64) + nt * 16 + lrow) * 8);
        sacc[nt] = __builtin_amdgcn_mfma_f32_16x16x32_bf16(aq[kc], bk, sacc[nt], 0, 0, 0);
      }
    }

    // mask + online softmax (rows = quad*4+r, cols = nt*16+lrow)
    int kbase = kt2 * 64;
    float sv[4][4];
#pragma unroll
    for (int nt = 0; nt < 4; ++nt)
#pragma unroll
      for (int r = 0; r < 4; ++r)
        sv[nt][r] = sacc[nt][r] +
                    attn_mask[(long)(qrow_c + r) * TOTK + kbase + nt * 16 + lrow];

    float alpha[4];
#pragma unroll
    for (int r = 0; r < 4; ++r) {
      float mx = fmaxf(fmaxf(sv[0][r], sv[1][r]), fmaxf(sv[2][r], sv[3][r]));
      mx = fmaxf(mx, __shfl_xor(mx, 1));
      mx = fmaxf(mx, __shfl_xor(mx, 2));
      mx = fmaxf(mx, __shfl_xor(mx, 4));
      mx = fmaxf(mx, __shfl_xor(mx, 8));
      float mn = fmaxf(m_r[r], mx);
      alpha[r] = __builtin_exp2f((m_r[r] - mn) * LOG2E);
      m_r[r] = mn;
      float rs = 0.f;
#pragma unroll
      for (int nt = 0; nt < 4; ++nt) {
        float p = __builtin_exp2f((sv[nt][r] - mn) * LOG2E);
        sv[nt][r] = p;
        rs += p;
      }
      rs += __shfl_xor(rs, 1);
      rs += __shfl_xor(rs, 2);
      rs += __shfl_xor(rs, 4);
      rs += __shfl_xor(rs, 8);
      l_r[r] = l_r[r] * alpha[r] + rs;
    }
#pragma unroll
    for (int v = 0; v < 8; ++v) {
      floatx4 c = cacc[v];
      c[0] *= alpha[0]; c[1] *= alpha[1]; c[2] *= alpha[2]; c[3] *= alpha[3];
      cacc[v] = c;
    }

    // P -> wave-private LDS (C-layout scatter), read back as A-operand.
    // Same wave writes AND reads its own region: compiler inserts the
    // wave-local lgkmcnt hazard wait; no block barrier needed.
    ushort_t* pw = &Pl[wave * 16 * 72];
#pragma unroll
    for (int nt = 0; nt < 4; ++nt)
#pragma unroll
      for (int r = 0; r < 4; ++r)
        pw[(quad * 4 + r) * 72 + nt * 16 + lrow] = f2bf(sv[nt][r]);

    const ushort_t* pr = &Pl[wave * 16 * 72];
    short8 ap[2];
#pragma unroll
    for (int kc = 0; kc < 2; ++kc)
      ap[kc] = *(const short8*)(pr + lrow * 72 + kc * 32 + quad * 8);

    // PV: V^T fragments straight from L2 (granule = row vd, 8 keys)
    const ushort_t* vs = Vbase + (long)kt2 * 1024 * 8;
#pragma unroll
    for (int kc = 0; kc < 2; ++kc) {
#pragma unroll
      for (int v = 0; v < 8; ++v) {
        short8 bv = *(const short8*)(vs + ((v * 16 + lrow) * 8 + kc * 4 + quad) * 8);
        cacc[v] = __builtin_amdgcn_mfma_f32_16x16x32_bf16(ap[kc], bv, cacc[v], 0, 0, 0);
      }
    }
  }

#pragma unroll
  for (int v = 0; v < 8; ++v)
#pragma unroll
    for (int r = 0; r < 4; ++r) {
      float o = cacc[v][r] / l_r[r];
      ctx[(long)(qrow_c + r) * 2048 + h * 128 + v * 16 + lrow] = f2bf(o);
    }
}

// ---------------------------------------------------------------------------
extern "C" void kernel_launch(void* const* d_in, const int* in_sizes, int n_in,
                              void* d_out, int out_size, void* d_ws, size_t ws_size,
                              hipStream_t stream)
{
  const float* hidden   = (const float*)d_in[0];
  const int*   pos      = (const int*)d_in[1];
  const float* mask     = (const float*)d_in[2];
  const float* past_k   = (const float*)d_in[3];
  const float* past_v   = (const float*)d_in[4];
  const float* w_in_ln  = (const float*)d_in[5];
  const float* w_qa     = (const float*)d_in[6];
  const float* w_qa_ln  = (const float*)d_in[7];
  const float* w_qb     = (const float*)d_in[8];
  const float* w_kva    = (const float*)d_in[9];
  const float* w_kva_ln = (const float*)d_in[10];
  const float* w_kvb    = (const float*)d_in[11];
  const float* w_o      = (const float*)d_in[12];

  float* out0  = (float*)d_out;                 // (2048, 5120)
  float* k_out = out0 + 10485760;               // (16, 4096, 192)
  float* v_out = k_out + 12582912;              // (16, 4096, 128)

  char* ws = (char*)d_ws;
  // Region A reused: x_bf (K1-K3) -> q_raw (gemm3) -> kv_raw (gemm4+)
  ushort_t* x_bf   = (ushort_t*)(ws + 0);            // 20,971,520 B max use
  ushort_t* q_raw  = x_bf;
  ushort_t* kv_raw = x_bf;
  ushort_t* qa_raw = (ushort_t*)(ws + 20971520);     // 6,291,456
  ushort_t* qa_n   = (ushort_t*)(ws + 27262976);     // 6,291,456
  ushort_t* ckv_raw= (ushort_t*)(ws + 33554432);     // 2,359,296
  ushort_t* ckv_n  = (ushort_t*)(ws + 35913728);     // 2,097,152
  ushort_t* kpe    = (ushort_t*)(ws + 38010880);     //   262,144
  ushort_t* q_bf   = (ushort_t*)(ws + 38273024);     // 12,582,912
  ushort_t* Kc     = (ushort_t*)(ws + 50855936);     // 25,165,824
  ushort_t* Vc     = (ushort_t*)(ws + 76021760);     // 16,777,216 (dense stride 8)
  ushort_t* ctx    = (ushort_t*)(ws + 94896128);     //  8,388,608  (end ~103.3 MB)

  // bf16 weight staging: Kc/Vc regions are dead until buildK/buildV;
  // Kc is dead again after attn (for w_o). All uses strictly ordered on stream.
  ushort_t* wqa_bf  = Kc;                               // 15,728,640
  ushort_t* wkva_bf = (ushort_t*)(ws + 50855936 + 15728640);  // 5,898,240 (ends 72.5MB < Vc)
  ushort_t* wqb_bf  = Vc;                               // 9,437,184
  ushort_t* wkvb_bf = (ushort_t*)(ws + 76021760 + 9437184);   // 4,194,304 (ends 89.7MB < ctx)
  ushort_t* wo_bf   = Kc;                               // 20,971,520 (after attn)

  cvt_kernel<<<dim3(3840), dim3(256), 0, stream>>>(w_qa, wqa_bf);    // 1536x5120
  cvt_kernel<<<dim3(1440), dim3(256), 0, stream>>>(w_kva, wkva_bf);  // 576x5120
  cvt_kernel<<<dim3(2304), dim3(256), 0, stream>>>(w_qb, wqb_bf);    // 3072x1536
  cvt_kernel<<<dim3(1024), dim3(256), 0, stream>>>(w_kvb, wkvb_bf);  // 4096x512

  rms_in_kernel<<<dim3(2048), dim3(320), 0, stream>>>(hidden, w_in_ln, x_bf);

  gemm_bt<<<dim3(12, 16), dim3(256), 0, stream>>>(x_bf, wqa_bf, qa_raw, (float*)nullptr,
                                                  (const float*)nullptr, 0.f, 2048, 1536, 5120);
  gemm_bt<<<dim3(5, 16), dim3(256), 0, stream>>>(x_bf, wkva_bf, ckv_raw, (float*)nullptr,
                                                 (const float*)nullptr, 0.f, 2048, 576, 5120);

  rms_qa_kernel<<<dim3(2048), dim3(192), 0, stream>>>(qa_raw, w_qa_ln, qa_n);
  rms_ckv_rope<<<dim3(2048), dim3(64), 0, stream>>>(ckv_raw, w_kva_ln, pos, ckv_n, kpe, k_out);

  gemm_bt<<<dim3(24, 16), dim3(256), 0, stream>>>(qa_n, wqb_bf, q_raw, (float*)nullptr,
                                                  (const float*)nullptr, 0.f, 2048, 3072, 1536);
  qpost_kernel<<<dim3(2048), dim3(256), 0, stream>>>(q_raw, pos, q_bf);

  gemm_bt<<<dim3(32, 16), dim3(256), 0, stream>>>(ckv_n, wkvb_bf, kv_raw, (float*)nullptr,
                                                  (const float*)nullptr, 0.f, 2048, 4096, 512);
  kvpost_kernel<<<dim3(2048), dim3(256), 0, stream>>>(kv_raw, k_out, v_out);
  past_kernel<<<dim3(10240), dim3(256), 0, stream>>>(past_k, past_v, k_out, v_out);

  buildK_kernel<<<dim3(6144), dim3(256), 0, stream>>>(past_k, kv_raw, kpe, Kc);
  buildV_kernel<<<dim3(4096), dim3(256), 0, stream>>>(past_v, kv_raw, Vc);

  attn_kernel<<<dim3(32, 16), dim3(256), 0, stream>>>(q_bf, Kc, Vc, mask, ctx);

  cvt_kernel<<<dim3(5120), dim3(256), 0, stream>>>(w_o, wo_bf);      // 5120x2048

  gemm_bt<<<dim3(40, 16), dim3(256), 0, stream>>>(ctx, wo_bf, (ushort_t*)nullptr, out0,
                                                  hidden, SCALE_DEV, 2048, 5120, 2048);
}

// Round 4
// 898.252 us; speedup vs baseline: 1.5697x; 1.5697x over previous
//
#include <hip/hip_runtime.h>
#include <cstdint>

typedef unsigned short ushort_t;
typedef __attribute__((ext_vector_type(8))) short short8;   // 8 bf16 in 4 VGPRs (guide §3)
typedef __attribute__((ext_vector_type(4))) float floatx4;

#define HID    5120
#define NHEAD  16
#define NOPE   128
#define ROPE_D 64
#define VDIM   128
#define QHD    192
#define QLORA  1536
#define KVLORA 512
#define SEQ    2048
#define PAST   2048
#define TOTK   4096
#define EPS_RMS 1e-6f
#define SCALE_DEV 0.125f
#define LOG2E 1.4426950408889634f
#define ATT_SCALE 0.07216878364870322f   /* 1/sqrt(192) */
#define LOG2_10000 13.287712379549449f

__device__ __forceinline__ float bf2f(ushort_t u) {
  unsigned int x = ((unsigned int)u) << 16;
  return __builtin_bit_cast(float, x);
}
__device__ __forceinline__ ushort_t f2bf(float f) {
  unsigned int u = __builtin_bit_cast(unsigned int, f);
  unsigned int r = u + 0x7fffu + ((u >> 16) & 1u);   // RNE
  return (ushort_t)(r >> 16);
}
__device__ __forceinline__ void unpack8(uint4 c, float* f) {
  const ushort_t* p = (const ushort_t*)&c;
#pragma unroll
  for (int i = 0; i < 8; ++i) f[i] = bf2f(p[i]);
}
__device__ __forceinline__ uint4 pack8(const float* f) {
  uint4 c;
  ushort_t* p = (ushort_t*)&c;
#pragma unroll
  for (int i = 0; i < 8; ++i) p[i] = f2bf(f[i]);
  return c;
}

// fp32 -> bf16 bulk convert, 8 elems/thread, exact grid (n % 8 == 0)
__global__ void cvt_kernel(const float* __restrict__ src, ushort_t* __restrict__ dst)
{
  long i = ((long)blockIdx.x * 256 + threadIdx.x) * 8;
  float f[8];
  *(float4*)(f)     = *(const float4*)(src + i);
  *(float4*)(f + 4) = *(const float4*)(src + i + 4);
  *(uint4*)(dst + i) = pack8(f);
}

// ---------------------------------------------------------------------------
// GEMM: C(MxN) = A(MxK,bf16,row-major) @ B(NxK,bf16,row-major)^T
// R0 structure (best measured on these skinny grids): 128x128 tile, BK=32,
// 4 waves x (64x64 via 4x4 16x16x32 MFMAs). LDS rows padded +8 bf16 (stride
// 40): fragment ds_read_b128 is 2-way (free). VGPR software prefetch of next
// K-slab. M%128==0, K%32==0; N guarded.
// ---------------------------------------------------------------------------
#define GLDT 40
__global__ __launch_bounds__(256, 2) void gemm_bt(
    const ushort_t* __restrict__ A, const ushort_t* __restrict__ B,
    ushort_t* __restrict__ Cb, float* __restrict__ Cf,
    const float* __restrict__ resid, float resid_scale,
    int M, int N, int K)
{
  __shared__ __align__(16) ushort_t As[128 * GLDT];
  __shared__ __align__(16) ushort_t Bs[128 * GLDT];
  int t = threadIdx.x;
  int lane = t & 63, wave = t >> 6;
  int wm = wave >> 1, wn = wave & 1;
  int lrow = lane & 15, quad = lane >> 4;
  long bm = (long)blockIdx.y * 128;
  long bn = (long)blockIdx.x * 128;

  int r0 = t >> 2, cc = t & 3;       // chunk 0: rows 0..63
  int r1 = r0 + 64;                  // chunk 1: rows 64..127
  const ushort_t* a0 = A + (bm + r0) * (long)K + cc * 8;
  const ushort_t* a1 = A + (bm + r1) * (long)K + cc * 8;
  long nb0 = bn + r0; if (nb0 > N - 1) nb0 = N - 1;
  long nb1 = bn + r1; if (nb1 > N - 1) nb1 = N - 1;
  const ushort_t* b0 = B + nb0 * (long)K + cc * 8;
  const ushort_t* b1 = B + nb1 * (long)K + cc * 8;

  floatx4 acc[4][4];
#pragma unroll
  for (int i = 0; i < 4; ++i)
#pragma unroll
    for (int j = 0; j < 4; ++j) acc[i][j] = (floatx4)0.f;

  uint4 pa0 = *(const uint4*)a0;
  uint4 pa1 = *(const uint4*)a1;
  uint4 pb0 = *(const uint4*)b0;
  uint4 pb1 = *(const uint4*)b1;

  int nk = K >> 5;
  for (int kt = 0; kt < nk; ++kt) {
    *(uint4*)&As[r0 * GLDT + cc * 8] = pa0;
    *(uint4*)&As[r1 * GLDT + cc * 8] = pa1;
    *(uint4*)&Bs[r0 * GLDT + cc * 8] = pb0;
    *(uint4*)&Bs[r1 * GLDT + cc * 8] = pb1;
    __syncthreads();
    if (kt + 1 < nk) {
      int off = (kt + 1) << 5;
      pa0 = *(const uint4*)(a0 + off);
      pa1 = *(const uint4*)(a1 + off);
      pb0 = *(const uint4*)(b0 + off);
      pb1 = *(const uint4*)(b1 + off);
    }
    short8 af[4], bfr[4];
#pragma unroll
    for (int mt = 0; mt < 4; ++mt)
      af[mt] = *(const short8*)&As[(wm * 64 + mt * 16 + lrow) * GLDT + quad * 8];
#pragma unroll
    for (int nt = 0; nt < 4; ++nt)
      bfr[nt] = *(const short8*)&Bs[(wn * 64 + nt * 16 + lrow) * GLDT + quad * 8];
#pragma unroll
    for (int mt = 0; mt < 4; ++mt)
#pragma unroll
      for (int nt = 0; nt < 4; ++nt)
        acc[mt][nt] = __builtin_amdgcn_mfma_f32_16x16x32_bf16(af[mt], bfr[nt], acc[mt][nt], 0, 0, 0);
    __syncthreads();
  }

  // epilogue: D layout col=lane&15, row=quad*4+reg (guide §3, m89-verified)
#pragma unroll
  for (int mt = 0; mt < 4; ++mt) {
    long grow = bm + wm * 64 + mt * 16 + quad * 4;
#pragma unroll
    for (int nt = 0; nt < 4; ++nt) {
      long gcol = bn + wn * 64 + nt * 16 + lrow;
      if (gcol < N) {
#pragma unroll
        for (int r2 = 0; r2 < 4; ++r2) {
          long row = grow + r2;
          float v = acc[mt][nt][r2];
          if (Cf) {
            if (resid) v += resid_scale * resid[row * (long)N + gcol];
            Cf[row * (long)N + gcol] = v;
          } else {
            Cb[row * (long)N + gcol] = f2bf(v);
          }
        }
      }
    }
  }
}

// ---------------------------------------------------------------------------
// RMSNorm kernels (fp32 inputs where they come from d_in)
// ---------------------------------------------------------------------------
__global__ void rms_in_kernel(const float* __restrict__ x,
                              const float* __restrict__ w,
                              ushort_t* __restrict__ out)
{
  int row = blockIdx.x, t = threadIdx.x;  // 320 threads, 16 elems each
  const float* xr = x + (long)row * HID + t * 16;
  float v[16];
#pragma unroll
  for (int i = 0; i < 4; ++i) *(float4*)(v + i * 4) = *(const float4*)(xr + i * 4);
  float ss = 0.f;
#pragma unroll
  for (int i = 0; i < 16; ++i) ss += v[i] * v[i];
#pragma unroll
  for (int o = 1; o < 64; o <<= 1) ss += __shfl_xor(ss, o);
  __shared__ float red[5];
  if ((t & 63) == 0) red[t >> 6] = ss;
  __syncthreads();
  float tot = red[0] + red[1] + red[2] + red[3] + red[4];
  float sc = rsqrtf(tot / (float)HID + EPS_RMS);
  float wv[16];
#pragma unroll
  for (int i = 0; i < 4; ++i) *(float4*)(wv + i * 4) = *(const float4*)(w + t * 16 + i * 4);
#pragma unroll
  for (int i = 0; i < 16; ++i) v[i] *= sc * wv[i];
  ushort_t* o = out + (long)row * HID + t * 16;
  *(uint4*)o       = pack8(v);
  *(uint4*)(o + 8) = pack8(v + 8);
}

__global__ void rms_qa_kernel(const ushort_t* __restrict__ x,
                              const float* __restrict__ w,
                              ushort_t* __restrict__ out)
{
  int row = blockIdx.x, t = threadIdx.x;  // 192 threads, 8 elems each
  const ushort_t* xr = x + (long)row * QLORA;
  float v[8];
  unpack8(*(const uint4*)(xr + t * 8), v);
  float ss = 0.f;
#pragma unroll
  for (int i = 0; i < 8; ++i) ss += v[i] * v[i];
#pragma unroll
  for (int o = 1; o < 64; o <<= 1) ss += __shfl_xor(ss, o);
  __shared__ float red[3];
  if ((t & 63) == 0) red[t >> 6] = ss;
  __syncthreads();
  float tot = red[0] + red[1] + red[2];
  float sc = rsqrtf(tot / (float)QLORA + EPS_RMS);
  float wv[8];
  *(float4*)(wv)     = *(const float4*)(w + t * 8);
  *(float4*)(wv + 4) = *(const float4*)(w + t * 8 + 4);
#pragma unroll
  for (int i = 0; i < 8; ++i) v[i] *= sc * wv[i];
  *(uint4*)(out + (long)row * QLORA + t * 8) = pack8(v);
}

// rmsnorm first 512 of ckv row (bf16 in); rope last 64 (k_pe):
// write bf16 ckv_n + bf16 kpe + fp32 k_out rope dims for all heads
__global__ void rms_ckv_rope(const ushort_t* __restrict__ ckv_raw,
                             const float* __restrict__ w,
                             const int* __restrict__ pos_ids,
                             ushort_t* __restrict__ ckv_n,
                             ushort_t* __restrict__ kpe,
                             float* __restrict__ k_out)
{
  int row = blockIdx.x, t = threadIdx.x;  // 64 threads (1 wave)
  const ushort_t* xr = ckv_raw + (long)row * 576;
  float v[8];
  unpack8(*(const uint4*)(xr + t * 8), v);
  float ss = 0.f;
#pragma unroll
  for (int i = 0; i < 8; ++i) ss += v[i] * v[i];
#pragma unroll
  for (int o = 1; o < 64; o <<= 1) ss += __shfl_xor(ss, o);
  float sc = rsqrtf(ss / (float)KVLORA + EPS_RMS);
  float wv[8];
  *(float4*)(wv)     = *(const float4*)(w + t * 8);
  *(float4*)(wv + 4) = *(const float4*)(w + t * 8 + 4);
  float ov[8];
#pragma unroll
  for (int i = 0; i < 8; ++i) ov[i] = v[i] * sc * wv[i];
  *(uint4*)(ckv_n + (long)row * KVLORA + t * 8) = pack8(ov);

  if (t < 32) {
    float e  = bf2f(xr[512 + 2 * t]);
    float od = bf2f(xr[512 + 2 * t + 1]);
    float p = (float)pos_ids[row];
    float inv = __builtin_exp2f(-((float)t / 32.f) * LOG2_10000);
    float ang = p * inv, sn, cs;
    sincosf(ang, &sn, &cs);
    float r1 = e * cs - od * sn;
    float r2 = od * cs + e * sn;
    kpe[(long)row * 64 + t]      = f2bf(r1);
    kpe[(long)row * 64 + 32 + t] = f2bf(r2);
#pragma unroll
    for (int h = 0; h < NHEAD; ++h) {
      float* kr = k_out + ((long)h * TOTK + PAST + row) * QHD + NOPE;
      kr[t] = r1;
      kr[32 + t] = r2;
    }
  }
}

// q post: scale nope by ATT_SCALE; rope+scale pe. q_raw/q_bf layout (s, 16, 192)
__global__ void qpost_kernel(const ushort_t* __restrict__ q_raw,
                             const int* __restrict__ pos_ids,
                             ushort_t* __restrict__ q_bf)
{
  int row = blockIdx.x, t = threadIdx.x;  // 256
  const ushort_t* qr = q_raw + (long)row * 3072;
  ushort_t* qo = q_bf + (long)row * 3072;
  {
    int hh = t >> 4, c = t & 15;
    float v[8];
    unpack8(*(const uint4*)(qr + hh * QHD + c * 8), v);
#pragma unroll
    for (int i = 0; i < 8; ++i) v[i] *= ATT_SCALE;
    *(uint4*)(qo + hh * QHD + c * 8) = pack8(v);
  }
  float p = (float)pos_ids[row];
#pragma unroll
  for (int it = 0; it < 2; ++it) {
    int slot = t + it * 256;
    int hh = slot >> 5, i = slot & 31;
    float e  = bf2f(qr[hh * QHD + NOPE + 2 * i]);
    float od = bf2f(qr[hh * QHD + NOPE + 2 * i + 1]);
    float inv = __builtin_exp2f(-((float)i / 32.f) * LOG2_10000);
    float ang = p * inv, sn, cs;
    sincosf(ang, &sn, &cs);
    qo[hh * QHD + NOPE + i]      = f2bf((e * cs - od * sn) * ATT_SCALE);
    qo[hh * QHD + NOPE + 32 + i] = f2bf((od * cs + e * sn) * ATT_SCALE);
  }
}

// kv post: split kv_raw (s, h*256 + [nope128|v128]) bf16 into fp32 k_out/v_out new rows
__global__ void kvpost_kernel(const ushort_t* __restrict__ kv_raw,
                              float* __restrict__ k_out,
                              float* __restrict__ v_out)
{
  int row = blockIdx.x, t = threadIdx.x;
  const ushort_t* kr = kv_raw + (long)row * 4096;
#pragma unroll
  for (int it = 0; it < 2; ++it) {
    int c = t + it * 256;
    int hh = c >> 5, cc = c & 31;
    float v[8];
    unpack8(*(const uint4*)(kr + c * 8), v);
    float* dst;
    if (cc < 16) dst = k_out + ((long)hh * TOTK + PAST + row) * QHD + cc * 8;
    else         dst = v_out + ((long)hh * TOTK + PAST + row) * VDIM + (cc - 16) * 8;
    floatx4 f0 = {v[0], v[1], v[2], v[3]};
    floatx4 f1 = {v[4], v[5], v[6], v[7]};
    *(floatx4*)dst = f0;
    *(floatx4*)(dst + 4) = f1;
  }
}

// past_k/past_v (fp32) -> fp32 k_out/v_out rows [0, PAST): strided copy, float4
__global__ void past_kernel(const float* __restrict__ past_k,
                            const float* __restrict__ past_v,
                            float* __restrict__ k_out,
                            float* __restrict__ v_out)
{
  long c = (long)blockIdx.x * 256 + threadIdx.x;  // chunk of 4 floats
  if (c < 1572864) {  // k: 16*2048*48 chunks
    float4 v = *(const float4*)(past_k + c * 4);
    long hh = c / 98304, rem = c % 98304;      // 2048*48 per head
    long s = rem / 48, cc = rem % 48;
    *(float4*)(k_out + (hh * (long)TOTK + s) * QHD + cc * 4) = v;
  } else {
    long c2 = c - 1572864;  // v: 16*2048*32 chunks
    float4 v = *(const float4*)(past_v + c2 * 4);
    long hh = c2 / 65536, rem = c2 % 65536;
    long s = rem / 32, cc = rem % 32;
    *(float4*)(v_out + (hh * (long)TOTK + s) * VDIM + cc * 4) = v;
  }
}

// Build attention-tiled bf16 K: granule g = ((h*64+kt)*24 + cc)*64 + ko (16B granules)
__global__ void buildK_kernel(const float* __restrict__ past_k,
                              const ushort_t* __restrict__ kv_raw,
                              const ushort_t* __restrict__ kpe,
                              ushort_t* __restrict__ Kc)
{
  long g = (long)blockIdx.x * 256 + threadIdx.x;  // < 1,572,864
  int ko = (int)(g & 63);
  long r = g >> 6;
  int cc = (int)(r % 24);
  long r2 = r / 24;
  int kt = (int)(r2 & 63);
  int hh = (int)(r2 >> 6);
  int key = kt * 64 + ko;
  uint4 val;
  if (key < PAST) {
    const float* src = past_k + ((long)hh * PAST + key) * QHD + cc * 8;
    float f[8];
    *(float4*)(f)     = *(const float4*)src;
    *(float4*)(f + 4) = *(const float4*)(src + 4);
    val = pack8(f);
  } else {
    int s = key - PAST;
    int d0 = cc * 8;
    if (d0 < NOPE) val = *(const uint4*)(kv_raw + (long)s * 4096 + hh * 256 + d0);
    else           val = *(const uint4*)(kpe + (long)s * 64 + (d0 - NOPE));
  }
  *(uint4*)(Kc + g * 8) = val;
}

// Build attention-tiled bf16 V^T: granule gv = ((h*64+kt)*128 + vd)*9 + kchunk
// (row stride 9 granules = 144B pad -> conflict-free b128 B-operand reads)
__global__ void buildV_kernel(const float* __restrict__ past_v,
                              const ushort_t* __restrict__ kv_raw,
                              ushort_t* __restrict__ Vc)
{
  long tid = (long)blockIdx.x * 256 + threadIdx.x;  // < 1,048,576
  int vd = (int)(tid & 127);
  long r = tid >> 7;
  int kchunk = (int)(r & 7);
  long r2 = r >> 3;
  int kt = (int)(r2 & 63);
  int hh = (int)(r2 >> 6);
  int key0 = kt * 64 + kchunk * 8;
  __align__(16) ushort_t tmp[8];
  if (key0 < PAST) {
#pragma unroll
    for (int j = 0; j < 8; ++j)
      tmp[j] = f2bf(past_v[((long)hh * PAST + key0 + j) * VDIM + vd]);
  } else {
    int s = key0 - PAST;
#pragma unroll
    for (int j = 0; j < 8; ++j)
      tmp[j] = kv_raw[(long)(s + j) * 4096 + hh * 256 + NOPE + vd];
  }
  *(uint4*)(Vc + ((((long)hh * 64 + kt) * 128 + vd) * 9 + kchunk) * 8) = *(uint4*)tmp;
}

// ---------------------------------------------------------------------------
// Flash attention, split-K x3 (flash-decoding): one block = (head, 64 q-rows,
// 1/3 of the key range). R0's verified loop body (stage->barrier->QK->softmax->
// wave-private-P->PV->barrier) unchanged; grid 512 -> 1536 blocks = 6/CU.
// LDS 52,224B -> 3 resident/CU = 12 waves/CU (R0 was grid-capped at 8):
// the 43% barrier/latency stall gets 1.5x the waves to hide under.
// 1536 = 2 x 768 -> two clean phases, no weak tail (split-2 would leave a
// 256-block 1-block/CU tail). Each section writes unnormalized partial O
// (bf16) + (m,l) (fp32) to workspace; combine_kernel merges the 3 partials.
// T5 setprio around MFMA clusters (attn-positive, m191).
// ---------------------------------------------------------------------------
__global__ __launch_bounds__(256, 3) void attn_kernel(
    const ushort_t* __restrict__ qb,        // (s,16,192) bf16, pre-scaled
    const ushort_t* __restrict__ Kc,        // tiled bf16
    const ushort_t* __restrict__ Vc,        // tiled bf16 (V^T, padded rows)
    const float* __restrict__ attn_mask,    // (2048,4096) fp32
    ushort_t* __restrict__ opart,           // (3,16,2048,128) bf16 partial O
    float* __restrict__ ml)                 // (3,16,2048) float2 {m,l}
{
  __shared__ __align__(16) ushort_t KtL[1536 * 8];
  __shared__ __align__(16) ushort_t VtL[1152 * 8];
  __shared__ __align__(16) ushort_t Pl[4 * 16 * 72];

  int t = threadIdx.x, lane = t & 63, wave = t >> 6;
  int lrow = lane & 15, quad = lane >> 4;
  // XCD swizzle: lb%8 = XCD. Phase 1 (lb<768): head = xcd; phase 2: xcd+8.
  // Per XCD working set = one head's K+V = 2.7MB < 4MB L2.
  int lb = blockIdx.x;                            // [0, 1536)
  int xcd = lb & 7, j = lb >> 3;                  // j in [0, 192)
  int h = xcd + 8 * (j / 96);
  int rem = j % 96;
  int sec = rem >> 5;                             // 0..2
  int q0 = (rem & 31) * 64;
  int kt_beg = (sec == 0) ? 0 : (sec == 1 ? 22 : 43);
  int kt_end = (sec == 0) ? 22 : (sec == 1 ? 43 : 64);
  int qrow_a = q0 + wave * 16 + lrow;
  int qrow_c = q0 + wave * 16 + quad * 4;

  short8 aq[6];
  const ushort_t* qp = qb + ((long)qrow_a * 16 + h) * QHD + quad * 8;
#pragma unroll
  for (int kc = 0; kc < 6; ++kc) aq[kc] = *(const short8*)(qp + kc * 32);

  float m_r[4], l_r[4];
  floatx4 cacc[8];
#pragma unroll
  for (int r = 0; r < 4; ++r) { m_r[r] = -1e30f; l_r[r] = 0.f; }
#pragma unroll
  for (int v = 0; v < 8; ++v) cacc[v] = (floatx4)0.f;

  const ushort_t* Kbase = Kc + (long)h * 64 * 1536 * 8;
  const ushort_t* Vbase = Vc + (long)h * 64 * 1152 * 8;

  for (int kt2 = kt_beg; kt2 < kt_end; ++kt2) {
    const ushort_t* ks = Kbase + (long)kt2 * 1536 * 8;
#pragma unroll
    for (int i = 0; i < 6; ++i) {
      int s = i * 256 + t;
      *(uint4*)&KtL[s * 8] = *(const uint4*)(ks + (long)s * 8);
    }
    const ushort_t* vs = Vbase + (long)kt2 * 1152 * 8;
#pragma unroll
    for (int i = 0; i < 5; ++i) {
      int s = i * 256 + t;
      if (s < 1152) *(uint4*)&VtL[s * 8] = *(const uint4*)(vs + (long)s * 8);
    }
    __syncthreads();

    // S = q . k  (scale pre-folded into q)
    floatx4 sacc[4];
#pragma unroll
    for (int nt = 0; nt < 4; ++nt) sacc[nt] = (floatx4)0.f;
    __builtin_amdgcn_s_setprio(1);
#pragma unroll
    for (int kc = 0; kc < 6; ++kc) {
#pragma unroll
      for (int nt = 0; nt < 4; ++nt) {
        short8 bk = *(const short8*)&KtL[(((kc * 4 + quad) * 64) + nt * 16 + lrow) * 8];
        sacc[nt] = __builtin_amdgcn_mfma_f32_16x16x32_bf16(aq[kc], bk, sacc[nt], 0, 0, 0);
      }
    }
    __builtin_amdgcn_s_setprio(0);

    // mask + online softmax (rows = quad*4+r, cols = nt*16+lrow)
    int kbase = kt2 * 64;
    float sv[4][4];
#pragma unroll
    for (int nt = 0; nt < 4; ++nt)
#pragma unroll
      for (int r = 0; r < 4; ++r)
        sv[nt][r] = sacc[nt][r] +
                    attn_mask[(long)(qrow_c + r) * TOTK + kbase + nt * 16 + lrow];

    float alpha[4];
#pragma unroll
    for (int r = 0; r < 4; ++r) {
      float mx = fmaxf(fmaxf(sv[0][r], sv[1][r]), fmaxf(sv[2][r], sv[3][r]));
      mx = fmaxf(mx, __shfl_xor(mx, 1));
      mx = fmaxf(mx, __shfl_xor(mx, 2));
      mx = fmaxf(mx, __shfl_xor(mx, 4));
      mx = fmaxf(mx, __shfl_xor(mx, 8));
      float mn = fmaxf(m_r[r], mx);
      alpha[r] = __builtin_exp2f((m_r[r] - mn) * LOG2E);
      m_r[r] = mn;
      float rs = 0.f;
#pragma unroll
      for (int nt = 0; nt < 4; ++nt) {
        float p = __builtin_exp2f((sv[nt][r] - mn) * LOG2E);
        sv[nt][r] = p;
        rs += p;
      }
      rs += __shfl_xor(rs, 1);
      rs += __shfl_xor(rs, 2);
      rs += __shfl_xor(rs, 4);
      rs += __shfl_xor(rs, 8);
      l_r[r] = l_r[r] * alpha[r] + rs;
    }
#pragma unroll
    for (int v = 0; v < 8; ++v) {
      floatx4 c = cacc[v];
      c[0] *= alpha[0]; c[1] *= alpha[1]; c[2] *= alpha[2]; c[3] *= alpha[3];
      cacc[v] = c;
    }

    // P -> wave-private LDS (C-layout scatter), read back as A-operand.
    // Same wave writes AND reads its region (HW-verified R2/R3): no block
    // barrier; compiler inserts the wave-local lgkmcnt hazard wait.
    ushort_t* pw = &Pl[wave * 16 * 72];
#pragma unroll
    for (int nt = 0; nt < 4; ++nt)
#pragma unroll
      for (int r = 0; r < 4; ++r)
        pw[(quad * 4 + r) * 72 + nt * 16 + lrow] = f2bf(sv[nt][r]);

    const ushort_t* pr = &Pl[wave * 16 * 72];
    short8 ap[2];
#pragma unroll
    for (int kc = 0; kc < 2; ++kc)
      ap[kc] = *(const short8*)(pr + lrow * 72 + kc * 32 + quad * 8);
    __builtin_amdgcn_s_setprio(1);
#pragma unroll
    for (int kc = 0; kc < 2; ++kc) {
#pragma unroll
      for (int v = 0; v < 8; ++v) {
        short8 bv = *(const short8*)&VtL[(((v * 16 + lrow) * 9) + kc * 4 + quad) * 8];
        cacc[v] = __builtin_amdgcn_mfma_f32_16x16x32_bf16(ap[kc], bv, cacc[v], 0, 0, 0);
      }
    }
    __builtin_amdgcn_s_setprio(0);
    __syncthreads();
  }

  // epilogue: unnormalized partial O (bf16) + (m,l) per row (fp32)
  long obase = (long)(sec * 16 + h) * 2048 + qrow_c;
#pragma unroll
  for (int v = 0; v < 8; ++v)
#pragma unroll
    for (int r = 0; r < 4; ++r)
      opart[(obase + r) * 128 + v * 16 + lrow] = f2bf(cacc[v][r]);
  if (lrow == 0) {
#pragma unroll
    for (int r = 0; r < 4; ++r) {
      float* mp = ml + (obase + r) * 2;
      mp[0] = m_r[r];
      mp[1] = l_r[r];
    }
  }
}

// Merge 3 split-K partials: ctx = (sum_s a_s*O_s) / (sum_s a_s*l_s),
// a_s = e^(m_s - M). 256 thr: 16 rows/block x 16 thr/row x 8 dims.
__global__ void combine_kernel(const ushort_t* __restrict__ opart,
                               const float* __restrict__ ml,
                               ushort_t* __restrict__ ctx)
{
  int t = threadIdx.x;
  int gr = blockIdx.x * 16 + (t >> 4);       // [0, 32768): h*2048 + qrow
  int h = gr >> 11, qrow = gr & 2047;
  int dc = (t & 15) * 8;
  float m[3], l[3];
#pragma unroll
  for (int s = 0; s < 3; ++s) {
    const float* p = ml + ((long)(s * 16 + h) * 2048 + qrow) * 2;
    m[s] = p[0]; l[s] = p[1];
  }
  float M = fmaxf(fmaxf(m[0], m[1]), m[2]);
  float aa[3], L = 0.f;
#pragma unroll
  for (int s = 0; s < 3; ++s) {
    aa[s] = __builtin_exp2f((m[s] - M) * LOG2E);
    L += aa[s] * l[s];
  }
  float inv = 1.f / L;
  float acc[8] = {0.f, 0.f, 0.f, 0.f, 0.f, 0.f, 0.f, 0.f};
#pragma unroll
  for (int s = 0; s < 3; ++s) {
    uint4 c = *(const uint4*)(opart + ((long)(s * 16 + h) * 2048 + qrow) * 128 + dc);
    float f[8];
    unpack8(c, f);
#pragma unroll
    for (int i = 0; i < 8; ++i) acc[i] += aa[s] * f[i];
  }
  float outv[8];
#pragma unroll
  for (int i = 0; i < 8; ++i) outv[i] = acc[i] * inv;
  *(uint4*)(ctx + (long)qrow * 2048 + h * 128 + dc) = pack8(outv);
}

// ---------------------------------------------------------------------------
extern "C" void kernel_launch(void* const* d_in, const int* in_sizes, int n_in,
                              void* d_out, int out_size, void* d_ws, size_t ws_size,
                              hipStream_t stream)
{
  const float* hidden   = (const float*)d_in[0];
  const int*   pos      = (const int*)d_in[1];
  const float* mask     = (const float*)d_in[2];
  const float* past_k   = (const float*)d_in[3];
  const float* past_v   = (const float*)d_in[4];
  const float* w_in_ln  = (const float*)d_in[5];
  const float* w_qa     = (const float*)d_in[6];
  const float* w_qa_ln  = (const float*)d_in[7];
  const float* w_qb     = (const float*)d_in[8];
  const float* w_kva    = (const float*)d_in[9];
  const float* w_kva_ln = (const float*)d_in[10];
  const float* w_kvb    = (const float*)d_in[11];
  const float* w_o      = (const float*)d_in[12];

  float* out0  = (float*)d_out;                 // (2048, 5120)
  float* k_out = out0 + 10485760;               // (16, 4096, 192)
  float* v_out = k_out + 12582912;              // (16, 4096, 128)

  char* ws = (char*)d_ws;
  // Region A reused: x_bf (K1-K3) -> q_raw (gemm3) -> kv_raw (gemm4+)
  // -> opart/ml (attn split partials; whole [0, 38.27MB) is dead during attn)
  ushort_t* x_bf   = (ushort_t*)(ws + 0);            // 20,971,520 B max use
  ushort_t* q_raw  = x_bf;
  ushort_t* kv_raw = x_bf;
  ushort_t* qa_raw = (ushort_t*)(ws + 20971520);     // 6,291,456
  ushort_t* qa_n   = (ushort_t*)(ws + 27262976);     // 6,291,456
  ushort_t* ckv_raw= (ushort_t*)(ws + 33554432);     // 2,359,296
  ushort_t* ckv_n  = (ushort_t*)(ws + 35913728);     // 2,097,152
  ushort_t* kpe    = (ushort_t*)(ws + 38010880);     //   262,144
  ushort_t* q_bf   = (ushort_t*)(ws + 38273024);     // 12,582,912
  ushort_t* Kc     = (ushort_t*)(ws + 50855936);     // 25,165,824
  ushort_t* Vc     = (ushort_t*)(ws + 76021760);     // 18,874,368
  ushort_t* ctx    = (ushort_t*)(ws + 94896128);     //  8,388,608  (end ~103.3 MB)

  // attn split-K partials (alias region A + qa/ckv/kpe, dead during attn):
  ushort_t* opart  = (ushort_t*)(ws + 0);            // 3*16*2048*128*2 = 25,165,824
  float*    mlbuf  = (float*)(ws + 25165824);        // 3*16*2048*8     =    786,432

  // bf16 weight staging: Kc/Vc regions are dead until buildK/buildV;
  // Kc is dead again after attn (for w_o). All uses strictly ordered on stream.
  ushort_t* wqa_bf  = Kc;                               // 15,728,640
  ushort_t* wkva_bf = (ushort_t*)(ws + 50855936 + 15728640);  // 5,898,240 (ends 72.5MB < Vc)
  ushort_t* wqb_bf  = Vc;                               // 9,437,184
  ushort_t* wkvb_bf = (ushort_t*)(ws + 76021760 + 9437184);   // 4,194,304 (ends 89.7MB < ctx)
  ushort_t* wo_bf   = Kc;                               // 20,971,520 (after attn)

  cvt_kernel<<<dim3(3840), dim3(256), 0, stream>>>(w_qa, wqa_bf);    // 1536x5120
  cvt_kernel<<<dim3(1440), dim3(256), 0, stream>>>(w_kva, wkva_bf);  // 576x5120
  cvt_kernel<<<dim3(2304), dim3(256), 0, stream>>>(w_qb, wqb_bf);    // 3072x1536
  cvt_kernel<<<dim3(1024), dim3(256), 0, stream>>>(w_kvb, wkvb_bf);  // 4096x512

  rms_in_kernel<<<dim3(2048), dim3(320), 0, stream>>>(hidden, w_in_ln, x_bf);

  gemm_bt<<<dim3(12, 16), dim3(256), 0, stream>>>(x_bf, wqa_bf, qa_raw, (float*)nullptr,
                                                  (const float*)nullptr, 0.f, 2048, 1536, 5120);
  gemm_bt<<<dim3(5, 16), dim3(256), 0, stream>>>(x_bf, wkva_bf, ckv_raw, (float*)nullptr,
                                                 (const float*)nullptr, 0.f, 2048, 576, 5120);

  rms_qa_kernel<<<dim3(2048), dim3(192), 0, stream>>>(qa_raw, w_qa_ln, qa_n);
  rms_ckv_rope<<<dim3(2048), dim3(64), 0, stream>>>(ckv_raw, w_kva_ln, pos, ckv_n, kpe, k_out);

  gemm_bt<<<dim3(24, 16), dim3(256), 0, stream>>>(qa_n, wqb_bf, q_raw, (float*)nullptr,
                                                  (const float*)nullptr, 0.f, 2048, 3072, 1536);
  qpost_kernel<<<dim3(2048), dim3(256), 0, stream>>>(q_raw, pos, q_bf);

  gemm_bt<<<dim3(32, 16), dim3(256), 0, stream>>>(ckv_n, wkvb_bf, kv_raw, (float*)nullptr,
                                                  (const float*)nullptr, 0.f, 2048, 4096, 512);
  kvpost_kernel<<<dim3(2048), dim3(256), 0, stream>>>(kv_raw, k_out, v_out);
  past_kernel<<<dim3(10240), dim3(256), 0, stream>>>(past_k, past_v, k_out, v_out);

  buildK_kernel<<<dim3(6144), dim3(256), 0, stream>>>(past_k, kv_raw, kpe, Kc);
  buildV_kernel<<<dim3(4096), dim3(256), 0, stream>>>(past_v, kv_raw, Vc);

  attn_kernel<<<dim3(1536), dim3(256), 0, stream>>>(q_bf, Kc, Vc, mask, opart, mlbuf);
  combine_kernel<<<dim3(2048), dim3(256), 0, stream>>>(opart, mlbuf, ctx);

  cvt_kernel<<<dim3(5120), dim3(256), 0, stream>>>(w_o, wo_bf);      // 5120x2048

  gemm_bt<<<dim3(40, 16), dim3(256), 0, stream>>>(ctx, wo_bf, (ushort_t*)nullptr, out0,
                                                  hidden, SCALE_DEV, 2048, 5120, 2048);
}

// Round 6
// 813.194 us; speedup vs baseline: 1.7339x; 1.1046x over previous
//
#include <hip/hip_runtime.h>
#include <cstdint>

typedef unsigned short ushort_t;
typedef __attribute__((ext_vector_type(8))) short short8;   // 8 bf16 in 4 VGPRs (guide §3)
typedef __attribute__((ext_vector_type(4))) float floatx4;

#define HID    5120
#define NHEAD  16
#define NOPE   128
#define ROPE_D 64
#define VDIM   128
#define QHD    192
#define QLORA  1536
#define KVLORA 512
#define SEQ    2048
#define PAST   2048
#define TOTK   4096
#define NQAKV  2112                     /* 1536 + 576 merged N */
#define EPS_RMS 1e-6f
#define SCALE_DEV 0.125f
#define LOG2E 1.4426950408889634f
#define ATT_SCALE 0.07216878364870322f   /* 1/sqrt(192) */
#define LOG2_10000 13.287712379549449f

__device__ __forceinline__ float bf2f(ushort_t u) {
  unsigned int x = ((unsigned int)u) << 16;
  return __builtin_bit_cast(float, x);
}
__device__ __forceinline__ ushort_t f2bf(float f) {
  unsigned int u = __builtin_bit_cast(unsigned int, f);
  unsigned int r = u + 0x7fffu + ((u >> 16) & 1u);   // RNE
  return (ushort_t)(r >> 16);
}
__device__ __forceinline__ void unpack8(uint4 c, float* f) {
  const ushort_t* p = (const ushort_t*)&c;
#pragma unroll
  for (int i = 0; i < 8; ++i) f[i] = bf2f(p[i]);
}
__device__ __forceinline__ uint4 pack8(const float* f) {
  uint4 c;
  ushort_t* p = (ushort_t*)&c;
#pragma unroll
  for (int i = 0; i < 8; ++i) p[i] = f2bf(f[i]);
  return c;
}

// fp32 -> bf16 bulk convert, 8 elems/thread, exact grid (n % 8 == 0)
__global__ void cvt_kernel(const float* __restrict__ src, ushort_t* __restrict__ dst)
{
  long i = ((long)blockIdx.x * 256 + threadIdx.x) * 8;
  float f[8];
  *(float4*)(f)     = *(const float4*)(src + i);
  *(float4*)(f + 4) = *(const float4*)(src + i + 4);
  *(uint4*)(dst + i) = pack8(f);
}

// zero a buffer, 16B/thread, exact grid
__global__ void zero4_kernel(uint4* __restrict__ dst)
{
  long i = (long)blockIdx.x * 256 + threadIdx.x;
  uint4 z; z.x = 0u; z.y = 0u; z.z = 0u; z.w = 0u;
  dst[i] = z;
}

// ---------------------------------------------------------------------------
// GEMM: C(MxN) = A(MxK,bf16,row-major) @ B(NxK,bf16,row-major)^T
// R0 structure (best measured on these skinny grids): 128x128 tile, BK=32,
// 4 waves x (64x64 via 4x4 16x16x32 MFMAs). LDS rows padded +8 bf16 (stride
// 40): fragment ds_read_b128 is 2-way (free). VGPR software prefetch of next
// K-slab. M%128==0, K%32==0; N guarded.
// ---------------------------------------------------------------------------
#define GLDT 40
__global__ __launch_bounds__(256, 2) void gemm_bt(
    const ushort_t* __restrict__ A, const ushort_t* __restrict__ B,
    ushort_t* __restrict__ Cb, float* __restrict__ Cf,
    const float* __restrict__ resid, float resid_scale,
    int M, int N, int K)
{
  __shared__ __align__(16) ushort_t As[128 * GLDT];
  __shared__ __align__(16) ushort_t Bs[128 * GLDT];
  int t = threadIdx.x;
  int lane = t & 63, wave = t >> 6;
  int wm = wave >> 1, wn = wave & 1;
  int lrow = lane & 15, quad = lane >> 4;
  long bm = (long)blockIdx.y * 128;
  long bn = (long)blockIdx.x * 128;

  int r0 = t >> 2, cc = t & 3;       // chunk 0: rows 0..63
  int r1 = r0 + 64;                  // chunk 1: rows 64..127
  const ushort_t* a0 = A + (bm + r0) * (long)K + cc * 8;
  const ushort_t* a1 = A + (bm + r1) * (long)K + cc * 8;
  long nb0 = bn + r0; if (nb0 > N - 1) nb0 = N - 1;
  long nb1 = bn + r1; if (nb1 > N - 1) nb1 = N - 1;
  const ushort_t* b0 = B + nb0 * (long)K + cc * 8;
  const ushort_t* b1 = B + nb1 * (long)K + cc * 8;

  floatx4 acc[4][4];
#pragma unroll
  for (int i = 0; i < 4; ++i)
#pragma unroll
    for (int j = 0; j < 4; ++j) acc[i][j] = (floatx4)0.f;

  uint4 pa0 = *(const uint4*)a0;
  uint4 pa1 = *(const uint4*)a1;
  uint4 pb0 = *(const uint4*)b0;
  uint4 pb1 = *(const uint4*)b1;

  int nk = K >> 5;
  for (int kt = 0; kt < nk; ++kt) {
    *(uint4*)&As[r0 * GLDT + cc * 8] = pa0;
    *(uint4*)&As[r1 * GLDT + cc * 8] = pa1;
    *(uint4*)&Bs[r0 * GLDT + cc * 8] = pb0;
    *(uint4*)&Bs[r1 * GLDT + cc * 8] = pb1;
    __syncthreads();
    if (kt + 1 < nk) {
      int off = (kt + 1) << 5;
      pa0 = *(const uint4*)(a0 + off);
      pa1 = *(const uint4*)(a1 + off);
      pb0 = *(const uint4*)(b0 + off);
      pb1 = *(const uint4*)(b1 + off);
    }
    short8 af[4], bfr[4];
#pragma unroll
    for (int mt = 0; mt < 4; ++mt)
      af[mt] = *(const short8*)&As[(wm * 64 + mt * 16 + lrow) * GLDT + quad * 8];
#pragma unroll
    for (int nt = 0; nt < 4; ++nt)
      bfr[nt] = *(const short8*)&Bs[(wn * 64 + nt * 16 + lrow) * GLDT + quad * 8];
#pragma unroll
    for (int mt = 0; mt < 4; ++mt)
#pragma unroll
      for (int nt = 0; nt < 4; ++nt)
        acc[mt][nt] = __builtin_amdgcn_mfma_f32_16x16x32_bf16(af[mt], bfr[nt], acc[mt][nt], 0, 0, 0);
    __syncthreads();
  }

  // epilogue: D layout col=lane&15, row=quad*4+reg (guide §3, m89-verified)
#pragma unroll
  for (int mt = 0; mt < 4; ++mt) {
    long grow = bm + wm * 64 + mt * 16 + quad * 4;
#pragma unroll
    for (int nt = 0; nt < 4; ++nt) {
      long gcol = bn + wn * 64 + nt * 16 + lrow;
      if (gcol < N) {
#pragma unroll
        for (int r2 = 0; r2 < 4; ++r2) {
          long row = grow + r2;
          float v = acc[mt][nt][r2];
          if (Cf) {
            if (resid) v += resid_scale * resid[row * (long)N + gcol];
            Cf[row * (long)N + gcol] = v;
          } else {
            Cb[row * (long)N + gcol] = f2bf(v);
          }
        }
      }
    }
  }
}

// ---------------------------------------------------------------------------
// Split-K GEMM (x2 via blockIdx.z): same tile structure as gemm_bt, but each
// z-slice computes a K-half and atomicAdds fp32 partials into pre-zeroed C.
// Deterministic: C starts 0, two commutative fp32 adds per element.
// Used for the merged qa|kva projection (N=2112, K=5120) -> 544 blocks
// instead of 192+80 serial underfilled blocks.
// ---------------------------------------------------------------------------
__global__ __launch_bounds__(256, 2) void gemm_splitk(
    const ushort_t* __restrict__ A, const ushort_t* __restrict__ B,
    float* __restrict__ Cf, int M, int N, int K)
{
  __shared__ __align__(16) ushort_t As[128 * GLDT];
  __shared__ __align__(16) ushort_t Bs[128 * GLDT];
  int t = threadIdx.x;
  int lane = t & 63, wave = t >> 6;
  int wm = wave >> 1, wn = wave & 1;
  int lrow = lane & 15, quad = lane >> 4;
  long bm = (long)blockIdx.y * 128;
  long bn = (long)blockIdx.x * 128;
  int khalf = K >> 1;
  long k0 = (long)blockIdx.z * khalf;

  int r0 = t >> 2, cc = t & 3;
  int r1 = r0 + 64;
  const ushort_t* a0 = A + (bm + r0) * (long)K + k0 + cc * 8;
  const ushort_t* a1 = A + (bm + r1) * (long)K + k0 + cc * 8;
  long nb0 = bn + r0; if (nb0 > N - 1) nb0 = N - 1;
  long nb1 = bn + r1; if (nb1 > N - 1) nb1 = N - 1;
  const ushort_t* b0 = B + nb0 * (long)K + k0 + cc * 8;
  const ushort_t* b1 = B + nb1 * (long)K + k0 + cc * 8;

  floatx4 acc[4][4];
#pragma unroll
  for (int i = 0; i < 4; ++i)
#pragma unroll
    for (int j = 0; j < 4; ++j) acc[i][j] = (floatx4)0.f;

  uint4 pa0 = *(const uint4*)a0;
  uint4 pa1 = *(const uint4*)a1;
  uint4 pb0 = *(const uint4*)b0;
  uint4 pb1 = *(const uint4*)b1;

  int nk = khalf >> 5;
  for (int kt = 0; kt < nk; ++kt) {
    *(uint4*)&As[r0 * GLDT + cc * 8] = pa0;
    *(uint4*)&As[r1 * GLDT + cc * 8] = pa1;
    *(uint4*)&Bs[r0 * GLDT + cc * 8] = pb0;
    *(uint4*)&Bs[r1 * GLDT + cc * 8] = pb1;
    __syncthreads();
    if (kt + 1 < nk) {
      int off = (kt + 1) << 5;
      pa0 = *(const uint4*)(a0 + off);
      pa1 = *(const uint4*)(a1 + off);
      pb0 = *(const uint4*)(b0 + off);
      pb1 = *(const uint4*)(b1 + off);
    }
    short8 af[4], bfr[4];
#pragma unroll
    for (int mt = 0; mt < 4; ++mt)
      af[mt] = *(const short8*)&As[(wm * 64 + mt * 16 + lrow) * GLDT + quad * 8];
#pragma unroll
    for (int nt = 0; nt < 4; ++nt)
      bfr[nt] = *(const short8*)&Bs[(wn * 64 + nt * 16 + lrow) * GLDT + quad * 8];
#pragma unroll
    for (int mt = 0; mt < 4; ++mt)
#pragma unroll
      for (int nt = 0; nt < 4; ++nt)
        acc[mt][nt] = __builtin_amdgcn_mfma_f32_16x16x32_bf16(af[mt], bfr[nt], acc[mt][nt], 0, 0, 0);
    __syncthreads();
  }

#pragma unroll
  for (int mt = 0; mt < 4; ++mt) {
    long grow = bm + wm * 64 + mt * 16 + quad * 4;
#pragma unroll
    for (int nt = 0; nt < 4; ++nt) {
      long gcol = bn + wn * 64 + nt * 16 + lrow;
      if (gcol < N) {
#pragma unroll
        for (int r2 = 0; r2 < 4; ++r2)
          atomicAdd(&Cf[(grow + r2) * (long)N + gcol], acc[mt][nt][r2]);
      }
    }
  }
}

// ---------------------------------------------------------------------------
// RMSNorm kernels
// ---------------------------------------------------------------------------
__global__ void rms_in_kernel(const float* __restrict__ x,
                              const float* __restrict__ w,
                              ushort_t* __restrict__ out)
{
  int row = blockIdx.x, t = threadIdx.x;  // 320 threads, 16 elems each
  const float* xr = x + (long)row * HID + t * 16;
  float v[16];
#pragma unroll
  for (int i = 0; i < 4; ++i) *(float4*)(v + i * 4) = *(const float4*)(xr + i * 4);
  float ss = 0.f;
#pragma unroll
  for (int i = 0; i < 16; ++i) ss += v[i] * v[i];
#pragma unroll
  for (int o = 1; o < 64; o <<= 1) ss += __shfl_xor(ss, o);
  __shared__ float red[5];
  if ((t & 63) == 0) red[t >> 6] = ss;
  __syncthreads();
  float tot = red[0] + red[1] + red[2] + red[3] + red[4];
  float sc = rsqrtf(tot / (float)HID + EPS_RMS);
  float wv[16];
#pragma unroll
  for (int i = 0; i < 4; ++i) *(float4*)(wv + i * 4) = *(const float4*)(w + t * 16 + i * 4);
#pragma unroll
  for (int i = 0; i < 16; ++i) v[i] *= sc * wv[i];
  ushort_t* o = out + (long)row * HID + t * 16;
  *(uint4*)o       = pack8(v);
  *(uint4*)(o + 8) = pack8(v + 8);
}

// rmsnorm over merged-C cols [0,1536) (fp32, stride 2112) -> bf16 qa_n
__global__ void rms_qa_f32(const float* __restrict__ C,
                           const float* __restrict__ w,
                           ushort_t* __restrict__ out)
{
  int row = blockIdx.x, t = threadIdx.x;  // 192 threads, 8 elems each
  const float* xr = C + (long)row * NQAKV + t * 8;
  float v[8];
  *(float4*)(v)     = *(const float4*)(xr);
  *(float4*)(v + 4) = *(const float4*)(xr + 4);
  float ss = 0.f;
#pragma unroll
  for (int i = 0; i < 8; ++i) ss += v[i] * v[i];
#pragma unroll
  for (int o = 1; o < 64; o <<= 1) ss += __shfl_xor(ss, o);
  __shared__ float red[3];
  if ((t & 63) == 0) red[t >> 6] = ss;
  __syncthreads();
  float tot = red[0] + red[1] + red[2];
  float sc = rsqrtf(tot / (float)QLORA + EPS_RMS);
  float wv[8];
  *(float4*)(wv)     = *(const float4*)(w + t * 8);
  *(float4*)(wv + 4) = *(const float4*)(w + t * 8 + 4);
#pragma unroll
  for (int i = 0; i < 8; ++i) v[i] *= sc * wv[i];
  *(uint4*)(out + (long)row * QLORA + t * 8) = pack8(v);
}

// rmsnorm merged-C cols [1536,2048) (c_kv); rope cols [2048,2112) (k_pe).
// fp32 input, stride 2112. Writes bf16 ckv_n + bf16 kpe + fp32 k_out rope dims.
__global__ void rms_ckv_rope_f32(const float* __restrict__ C,
                                 const float* __restrict__ w,
                                 const int* __restrict__ pos_ids,
                                 ushort_t* __restrict__ ckv_n,
                                 ushort_t* __restrict__ kpe,
                                 float* __restrict__ k_out)
{
  int row = blockIdx.x, t = threadIdx.x;  // 64 threads (1 wave)
  const float* xr = C + (long)row * NQAKV + QLORA;
  float v[8];
  *(float4*)(v)     = *(const float4*)(xr + t * 8);
  *(float4*)(v + 4) = *(const float4*)(xr + t * 8 + 4);
  float ss = 0.f;
#pragma unroll
  for (int i = 0; i < 8; ++i) ss += v[i] * v[i];
#pragma unroll
  for (int o = 1; o < 64; o <<= 1) ss += __shfl_xor(ss, o);
  float sc = rsqrtf(ss / (float)KVLORA + EPS_RMS);
  float wv[8];
  *(float4*)(wv)     = *(const float4*)(w + t * 8);
  *(float4*)(wv + 4) = *(const float4*)(w + t * 8 + 4);
  float ov[8];
#pragma unroll
  for (int i = 0; i < 8; ++i) ov[i] = v[i] * sc * wv[i];
  *(uint4*)(ckv_n + (long)row * KVLORA + t * 8) = pack8(ov);

  if (t < 32) {
    float e  = xr[512 + 2 * t];
    float od = xr[512 + 2 * t + 1];
    float p = (float)pos_ids[row];
    float inv = __builtin_exp2f(-((float)t / 32.f) * LOG2_10000);
    float ang = p * inv, sn, cs;
    sincosf(ang, &sn, &cs);
    float r1 = e * cs - od * sn;
    float r2 = od * cs + e * sn;
    kpe[(long)row * 64 + t]      = f2bf(r1);
    kpe[(long)row * 64 + 32 + t] = f2bf(r2);
#pragma unroll
    for (int h = 0; h < NHEAD; ++h) {
      float* kr = k_out + ((long)h * TOTK + PAST + row) * QHD + NOPE;
      kr[t] = r1;
      kr[32 + t] = r2;
    }
  }
}

// q post: scale nope by ATT_SCALE; rope+scale pe. q_raw/q_bf layout (s, 16, 192)
__global__ void qpost_kernel(const ushort_t* __restrict__ q_raw,
                             const int* __restrict__ pos_ids,
                             ushort_t* __restrict__ q_bf)
{
  int row = blockIdx.x, t = threadIdx.x;  // 256
  const ushort_t* qr = q_raw + (long)row * 3072;
  ushort_t* qo = q_bf + (long)row * 3072;
  {
    int hh = t >> 4, c = t & 15;
    float v[8];
    unpack8(*(const uint4*)(qr + hh * QHD + c * 8), v);
#pragma unroll
    for (int i = 0; i < 8; ++i) v[i] *= ATT_SCALE;
    *(uint4*)(qo + hh * QHD + c * 8) = pack8(v);
  }
  float p = (float)pos_ids[row];
#pragma unroll
  for (int it = 0; it < 2; ++it) {
    int slot = t + it * 256;
    int hh = slot >> 5, i = slot & 31;
    float e  = bf2f(qr[hh * QHD + NOPE + 2 * i]);
    float od = bf2f(qr[hh * QHD + NOPE + 2 * i + 1]);
    float inv = __builtin_exp2f(-((float)i / 32.f) * LOG2_10000);
    float ang = p * inv, sn, cs;
    sincosf(ang, &sn, &cs);
    qo[hh * QHD + NOPE + i]      = f2bf((e * cs - od * sn) * ATT_SCALE);
    qo[hh * QHD + NOPE + 32 + i] = f2bf((od * cs + e * sn) * ATT_SCALE);
  }
}

// kv post: split kv_raw (s, h*256 + [nope128|v128]) bf16 into fp32 k_out/v_out new rows
__global__ void kvpost_kernel(const ushort_t* __restrict__ kv_raw,
                              float* __restrict__ k_out,
                              float* __restrict__ v_out)
{
  int row = blockIdx.x, t = threadIdx.x;
  const ushort_t* kr = kv_raw + (long)row * 4096;
#pragma unroll
  for (int it = 0; it < 2; ++it) {
    int c = t + it * 256;
    int hh = c >> 5, cc = c & 31;
    float v[8];
    unpack8(*(const uint4*)(kr + c * 8), v);
    float* dst;
    if (cc < 16) dst = k_out + ((long)hh * TOTK + PAST + row) * QHD + cc * 8;
    else         dst = v_out + ((long)hh * TOTK + PAST + row) * VDIM + (cc - 16) * 8;
    floatx4 f0 = {v[0], v[1], v[2], v[3]};
    floatx4 f1 = {v[4], v[5], v[6], v[7]};
    *(floatx4*)dst = f0;
    *(floatx4*)(dst + 4) = f1;
  }
}

// past_k/past_v (fp32) -> fp32 k_out/v_out rows [0, PAST): strided copy, float4
__global__ void past_kernel(const float* __restrict__ past_k,
                            const float* __restrict__ past_v,
                            float* __restrict__ k_out,
                            float* __restrict__ v_out)
{
  long c = (long)blockIdx.x * 256 + threadIdx.x;  // chunk of 4 floats
  if (c < 1572864) {  // k: 16*2048*48 chunks
    float4 v = *(const float4*)(past_k + c * 4);
    long hh = c / 98304, rem = c % 98304;      // 2048*48 per head
    long s = rem / 48, cc = rem % 48;
    *(float4*)(k_out + (hh * (long)TOTK + s) * QHD + cc * 4) = v;
  } else {
    long c2 = c - 1572864;  // v: 16*2048*32 chunks
    float4 v = *(const float4*)(past_v + c2 * 4);
    long hh = c2 / 65536, rem = c2 % 65536;
    long s = rem / 32, cc = rem % 32;
    *(float4*)(v_out + (hh * (long)TOTK + s) * VDIM + cc * 4) = v;
  }
}

// Build attention-tiled bf16 K: granule g = ((h*64+kt)*24 + cc)*64 + ko (16B granules)
__global__ void buildK_kernel(const float* __restrict__ past_k,
                              const ushort_t* __restrict__ kv_raw,
                              const ushort_t* __restrict__ kpe,
                              ushort_t* __restrict__ Kc)
{
  long g = (long)blockIdx.x * 256 + threadIdx.x;  // < 1,572,864
  int ko = (int)(g & 63);
  long r = g >> 6;
  int cc = (int)(r % 24);
  long r2 = r / 24;
  int kt = (int)(r2 & 63);
  int hh = (int)(r2 >> 6);
  int key = kt * 64 + ko;
  uint4 val;
  if (key < PAST) {
    const float* src = past_k + ((long)hh * PAST + key) * QHD + cc * 8;
    float f[8];
    *(float4*)(f)     = *(const float4*)src;
    *(float4*)(f + 4) = *(const float4*)(src + 4);
    val = pack8(f);
  } else {
    int s = key - PAST;
    int d0 = cc * 8;
    if (d0 < NOPE) val = *(const uint4*)(kv_raw + (long)s * 4096 + hh * 256 + d0);
    else           val = *(const uint4*)(kpe + (long)s * 64 + (d0 - NOPE));
  }
  *(uint4*)(Kc + g * 8) = val;
}

// Build attention-tiled bf16 V^T: granule gv = ((h*64+kt)*128 + vd)*9 + kchunk
// (row stride 9 granules = 144B pad -> conflict-free b128 B-operand reads)
__global__ void buildV_kernel(const float* __restrict__ past_v,
                              const ushort_t* __restrict__ kv_raw,
                              ushort_t* __restrict__ Vc)
{
  long tid = (long)blockIdx.x * 256 + threadIdx.x;  // < 1,048,576
  int vd = (int)(tid & 127);
  long r = tid >> 7;
  int kchunk = (int)(r & 7);
  long r2 = r >> 3;
  int kt = (int)(r2 & 63);
  int hh = (int)(r2 >> 6);
  int key0 = kt * 64 + kchunk * 8;
  __align__(16) ushort_t tmp[8];
  if (key0 < PAST) {
#pragma unroll
    for (int j = 0; j < 8; ++j)
      tmp[j] = f2bf(past_v[((long)hh * PAST + key0 + j) * VDIM + vd]);
  } else {
    int s = key0 - PAST;
#pragma unroll
    for (int j = 0; j < 8; ++j)
      tmp[j] = kv_raw[(long)(s + j) * 4096 + hh * 256 + NOPE + vd];
  }
  *(uint4*)(Vc + ((((long)hh * 64 + kt) * 128 + vd) * 9 + kchunk) * 8) = *(uint4*)tmp;
}

// ---------------------------------------------------------------------------
// Flash attention, split-K x3 (R4-verified structure) + T13 defer-max:
// skip the alpha-rescale of cacc when no row's tile-max exceeds m+8
// (P bounded by e^8, bf16-safe; guide m214v23, +5%).
// ---------------------------------------------------------------------------
__global__ __launch_bounds__(256, 3) void attn_kernel(
    const ushort_t* __restrict__ qb,        // (s,16,192) bf16, pre-scaled
    const ushort_t* __restrict__ Kc,        // tiled bf16
    const ushort_t* __restrict__ Vc,        // tiled bf16 (V^T, padded rows)
    const float* __restrict__ attn_mask,    // (2048,4096) fp32
    ushort_t* __restrict__ opart,           // (3,16,2048,128) bf16 partial O
    float* __restrict__ ml)                 // (3,16,2048) float2 {m,l}
{
  __shared__ __align__(16) ushort_t KtL[1536 * 8];
  __shared__ __align__(16) ushort_t VtL[1152 * 8];
  __shared__ __align__(16) ushort_t Pl[4 * 16 * 72];

  int t = threadIdx.x, lane = t & 63, wave = t >> 6;
  int lrow = lane & 15, quad = lane >> 4;
  int lb = blockIdx.x;                            // [0, 1536)
  int xcd = lb & 7, j = lb >> 3;                  // j in [0, 192)
  int h = xcd + 8 * (j / 96);
  int rem = j % 96;
  int sec = rem >> 5;                             // 0..2
  int q0 = (rem & 31) * 64;
  int kt_beg = (sec == 0) ? 0 : (sec == 1 ? 22 : 43);
  int kt_end = (sec == 0) ? 22 : (sec == 1 ? 43 : 64);
  int qrow_a = q0 + wave * 16 + lrow;
  int qrow_c = q0 + wave * 16 + quad * 4;

  short8 aq[6];
  const ushort_t* qp = qb + ((long)qrow_a * 16 + h) * QHD + quad * 8;
#pragma unroll
  for (int kc = 0; kc < 6; ++kc) aq[kc] = *(const short8*)(qp + kc * 32);

  float m_r[4], l_r[4];
  floatx4 cacc[8];
#pragma unroll
  for (int r = 0; r < 4; ++r) { m_r[r] = -1e30f; l_r[r] = 0.f; }
#pragma unroll
  for (int v = 0; v < 8; ++v) cacc[v] = (floatx4)0.f;

  const ushort_t* Kbase = Kc + (long)h * 64 * 1536 * 8;
  const ushort_t* Vbase = Vc + (long)h * 64 * 1152 * 8;

  for (int kt2 = kt_beg; kt2 < kt_end; ++kt2) {
    const ushort_t* ks = Kbase + (long)kt2 * 1536 * 8;
#pragma unroll
    for (int i = 0; i < 6; ++i) {
      int s = i * 256 + t;
      *(uint4*)&KtL[s * 8] = *(const uint4*)(ks + (long)s * 8);
    }
    const ushort_t* vs = Vbase + (long)kt2 * 1152 * 8;
#pragma unroll
    for (int i = 0; i < 5; ++i) {
      int s = i * 256 + t;
      if (s < 1152) *(uint4*)&VtL[s * 8] = *(const uint4*)(vs + (long)s * 8);
    }
    __syncthreads();

    // S = q . k  (scale pre-folded into q)
    floatx4 sacc[4];
#pragma unroll
    for (int nt = 0; nt < 4; ++nt) sacc[nt] = (floatx4)0.f;
    __builtin_amdgcn_s_setprio(1);
#pragma unroll
    for (int kc = 0; kc < 6; ++kc) {
#pragma unroll
      for (int nt = 0; nt < 4; ++nt) {
        short8 bk = *(const short8*)&KtL[(((kc * 4 + quad) * 64) + nt * 16 + lrow) * 8];
        sacc[nt] = __builtin_amdgcn_mfma_f32_16x16x32_bf16(aq[kc], bk, sacc[nt], 0, 0, 0);
      }
    }
    __builtin_amdgcn_s_setprio(0);

    // mask + online softmax (rows = quad*4+r, cols = nt*16+lrow)
    int kbase = kt2 * 64;
    float sv[4][4];
#pragma unroll
    for (int nt = 0; nt < 4; ++nt)
#pragma unroll
      for (int r = 0; r < 4; ++r)
        sv[nt][r] = sacc[nt][r] +
                    attn_mask[(long)(qrow_c + r) * TOTK + kbase + nt * 16 + lrow];

    // row-max reduce + T13 defer-max decision
    float mxv[4]; int need = 0;
#pragma unroll
    for (int r = 0; r < 4; ++r) {
      float mx = fmaxf(fmaxf(sv[0][r], sv[1][r]), fmaxf(sv[2][r], sv[3][r]));
      mx = fmaxf(mx, __shfl_xor(mx, 1));
      mx = fmaxf(mx, __shfl_xor(mx, 2));
      mx = fmaxf(mx, __shfl_xor(mx, 4));
      mx = fmaxf(mx, __shfl_xor(mx, 8));
      mxv[r] = mx;
      need |= (mx > m_r[r] + 8.f) ? 1 : 0;
    }
    float alpha[4] = {1.f, 1.f, 1.f, 1.f};
    if (__any(need)) {
#pragma unroll
      for (int r = 0; r < 4; ++r) {
        float mn = fmaxf(m_r[r], mxv[r]);
        alpha[r] = __builtin_exp2f((m_r[r] - mn) * LOG2E);
        m_r[r] = mn;
      }
#pragma unroll
      for (int v = 0; v < 8; ++v) {
        floatx4 c = cacc[v];
        c[0] *= alpha[0]; c[1] *= alpha[1]; c[2] *= alpha[2]; c[3] *= alpha[3];
        cacc[v] = c;
      }
    }
#pragma unroll
    for (int r = 0; r < 4; ++r) {
      float rs = 0.f;
#pragma unroll
      for (int nt = 0; nt < 4; ++nt) {
        float p = __builtin_exp2f((sv[nt][r] - m_r[r]) * LOG2E);
        sv[nt][r] = p;
        rs += p;
      }
      rs += __shfl_xor(rs, 1);
      rs += __shfl_xor(rs, 2);
      rs += __shfl_xor(rs, 4);
      rs += __shfl_xor(rs, 8);
      l_r[r] = l_r[r] * alpha[r] + rs;
    }

    // P -> wave-private LDS (C-layout scatter), read back as A-operand.
    ushort_t* pw = &Pl[wave * 16 * 72];
#pragma unroll
    for (int nt = 0; nt < 4; ++nt)
#pragma unroll
      for (int r = 0; r < 4; ++r)
        pw[(quad * 4 + r) * 72 + nt * 16 + lrow] = f2bf(sv[nt][r]);

    const ushort_t* pr = &Pl[wave * 16 * 72];
    short8 ap[2];
#pragma unroll
    for (int kc = 0; kc < 2; ++kc)
      ap[kc] = *(const short8*)(pr + lrow * 72 + kc * 32 + quad * 8);
    __builtin_amdgcn_s_setprio(1);
#pragma unroll
    for (int kc = 0; kc < 2; ++kc) {
#pragma unroll
      for (int v = 0; v < 8; ++v) {
        short8 bv = *(const short8*)&VtL[(((v * 16 + lrow) * 9) + kc * 4 + quad) * 8];
        cacc[v] = __builtin_amdgcn_mfma_f32_16x16x32_bf16(ap[kc], bv, cacc[v], 0, 0, 0);
      }
    }
    __builtin_amdgcn_s_setprio(0);
    __syncthreads();
  }

  // epilogue: unnormalized partial O (bf16) + (m,l) per row (fp32)
  long obase = (long)(sec * 16 + h) * 2048 + qrow_c;
#pragma unroll
  for (int v = 0; v < 8; ++v)
#pragma unroll
    for (int r = 0; r < 4; ++r)
      opart[(obase + r) * 128 + v * 16 + lrow] = f2bf(cacc[v][r]);
  if (lrow == 0) {
#pragma unroll
    for (int r = 0; r < 4; ++r) {
      float* mp = ml + (obase + r) * 2;
      mp[0] = m_r[r];
      mp[1] = l_r[r];
    }
  }
}

// Merge 3 split-K partials: ctx = (sum_s a_s*O_s) / (sum_s a_s*l_s),
// a_s = e^(m_s - M). 256 thr: 16 rows/block x 16 thr/row x 8 dims.
__global__ void combine_kernel(const ushort_t* __restrict__ opart,
                               const float* __restrict__ ml,
                               ushort_t* __restrict__ ctx)
{
  int t = threadIdx.x;
  int gr = blockIdx.x * 16 + (t >> 4);       // [0, 32768): h*2048 + qrow
  int h = gr >> 11, qrow = gr & 2047;
  int dc = (t & 15) * 8;
  float m[3], l[3];
#pragma unroll
  for (int s = 0; s < 3; ++s) {
    const float* p = ml + ((long)(s * 16 + h) * 2048 + qrow) * 2;
    m[s] = p[0]; l[s] = p[1];
  }
  float M = fmaxf(fmaxf(m[0], m[1]), m[2]);
  float aa[3], L = 0.f;
#pragma unroll
  for (int s = 0; s < 3; ++s) {
    aa[s] = __builtin_exp2f((m[s] - M) * LOG2E);
    L += aa[s] * l[s];
  }
  float inv = 1.f / L;
  float acc[8] = {0.f, 0.f, 0.f, 0.f, 0.f, 0.f, 0.f, 0.f};
#pragma unroll
  for (int s = 0; s < 3; ++s) {
    uint4 c = *(const uint4*)(opart + ((long)(s * 16 + h) * 2048 + qrow) * 128 + dc);
    float f[8];
    unpack8(c, f);
#pragma unroll
    for (int i = 0; i < 8; ++i) acc[i] += aa[s] * f[i];
  }
  float outv[8];
#pragma unroll
  for (int i = 0; i < 8; ++i) outv[i] = acc[i] * inv;
  *(uint4*)(ctx + (long)qrow * 2048 + h * 128 + dc) = pack8(outv);
}

// ---------------------------------------------------------------------------
extern "C" void kernel_launch(void* const* d_in, const int* in_sizes, int n_in,
                              void* d_out, int out_size, void* d_ws, size_t ws_size,
                              hipStream_t stream)
{
  const float* hidden   = (const float*)d_in[0];
  const int*   pos      = (const int*)d_in[1];
  const float* mask     = (const float*)d_in[2];
  const float* past_k   = (const float*)d_in[3];
  const float* past_v   = (const float*)d_in[4];
  const float* w_in_ln  = (const float*)d_in[5];
  const float* w_qa     = (const float*)d_in[6];
  const float* w_qa_ln  = (const float*)d_in[7];
  const float* w_qb     = (const float*)d_in[8];
  const float* w_kva    = (const float*)d_in[9];
  const float* w_kva_ln = (const float*)d_in[10];
  const float* w_kvb    = (const float*)d_in[11];
  const float* w_o      = (const float*)d_in[12];

  float* out0  = (float*)d_out;                 // (2048, 5120)
  float* k_out = out0 + 10485760;               // (16, 4096, 192)
  float* v_out = k_out + 12582912;              // (16, 4096, 128)

  char* ws = (char*)d_ws;
  // Timeline-disjoint layout (all aliases ordered on the single stream):
  //   [0,        20.97MB)  x_bf -> q_raw -> kv_raw -> opart(attn)
  //   [20.97MB,  38.27MB)  C fp32 (2048x2112, merged qa|ckv) -> opart tail/ml
  //   [38.27MB,  50.86MB)  qa_n (first 6.3MB) -> q_bf (full 12.58MB)
  //   [50.86MB,  76.02MB)  wqakva_bf (21.6MB) -> Kc (buildK) -> wo_bf
  //   [76.02MB,  94.90MB)  wqb_bf/wkvb_bf -> Vc (buildV)
  //   [94.90MB, 103.28MB)  ckv_n+kpe -> ctx (combine)
  ushort_t* x_bf   = (ushort_t*)(ws + 0);
  ushort_t* q_raw  = x_bf;
  ushort_t* kv_raw = x_bf;
  float*    Cqakv  = (float*)(ws + 20971520);        // 17,301,504 B
  ushort_t* qa_n   = (ushort_t*)(ws + 38273024);     // 6,291,456 (borrows q_bf head)
  ushort_t* q_bf   = (ushort_t*)(ws + 38273024);     // 12,582,912
  ushort_t* Kc     = (ushort_t*)(ws + 50855936);     // 25,165,824
  ushort_t* Vc     = (ushort_t*)(ws + 76021760);     // 18,874,368
  ushort_t* ckv_n  = (ushort_t*)(ws + 94896128);     // 2,097,152
  ushort_t* kpe    = (ushort_t*)(ws + 96993280);     //   262,144
  ushort_t* ctx    = (ushort_t*)(ws + 94896128);     // 8,388,608 (after ckv_n/kpe dead)

  // attn split-K partials (regions A + C dead during attn)
  ushort_t* opart  = (ushort_t*)(ws + 0);            // 25,165,824
  float*    mlbuf  = (float*)(ws + 25165824);        //    786,432

  // bf16 weight staging
  ushort_t* wqakva_bf = Kc;                                    // 21,626,880
  ushort_t* wqb_bf    = Vc;                                    //  9,437,184
  ushort_t* wkvb_bf   = (ushort_t*)(ws + 76021760 + 9437184);  //  4,194,304
  ushort_t* wo_bf     = Kc;                                    // 20,971,520 (after attn)

  cvt_kernel<<<dim3(3840), dim3(256), 0, stream>>>(w_qa, wqakva_bf);            // 1536x5120
  cvt_kernel<<<dim3(1440), dim3(256), 0, stream>>>(w_kva, wqakva_bf + 7864320); // 576x5120
  cvt_kernel<<<dim3(2304), dim3(256), 0, stream>>>(w_qb, wqb_bf);               // 3072x1536
  cvt_kernel<<<dim3(1024), dim3(256), 0, stream>>>(w_kvb, wkvb_bf);             // 4096x512

  zero4_kernel<<<dim3(4224), dim3(256), 0, stream>>>((uint4*)Cqakv);  // 17,301,504 B

  rms_in_kernel<<<dim3(2048), dim3(320), 0, stream>>>(hidden, w_in_ln, x_bf);

  // merged qa|kva projection, split-K x2 -> 544 blocks (was 192+80 serial)
  gemm_splitk<<<dim3(17, 16, 2), dim3(256), 0, stream>>>(x_bf, wqakva_bf, Cqakv,
                                                         2048, NQAKV, 5120);

  rms_qa_f32<<<dim3(2048), dim3(192), 0, stream>>>(Cqakv, w_qa_ln, qa_n);
  rms_ckv_rope_f32<<<dim3(2048), dim3(64), 0, stream>>>(Cqakv, w_kva_ln, pos,
                                                        ckv_n, kpe, k_out);

  gemm_bt<<<dim3(24, 16), dim3(256), 0, stream>>>(qa_n, wqb_bf, q_raw, (float*)nullptr,
                                                  (const float*)nullptr, 0.f, 2048, 3072, 1536);
  qpost_kernel<<<dim3(2048), dim3(256), 0, stream>>>(q_raw, pos, q_bf);

  gemm_bt<<<dim3(32, 16), dim3(256), 0, stream>>>(ckv_n, wkvb_bf, kv_raw, (float*)nullptr,
                                                  (const float*)nullptr, 0.f, 2048, 4096, 512);
  kvpost_kernel<<<dim3(2048), dim3(256), 0, stream>>>(kv_raw, k_out, v_out);
  past_kernel<<<dim3(10240), dim3(256), 0, stream>>>(past_k, past_v, k_out, v_out);

  buildK_kernel<<<dim3(6144), dim3(256), 0, stream>>>(past_k, kv_raw, kpe, Kc);
  buildV_kernel<<<dim3(4096), dim3(256), 0, stream>>>(past_v, kv_raw, Vc);

  attn_kernel<<<dim3(1536), dim3(256), 0, stream>>>(q_bf, Kc, Vc, mask, opart, mlbuf);
  combine_kernel<<<dim3(2048), dim3(256), 0, stream>>>(opart, mlbuf, ctx);

  cvt_kernel<<<dim3(5120), dim3(256), 0, stream>>>(w_o, wo_bf);      // 5120x2048

  gemm_bt<<<dim3(40, 16), dim3(256), 0, stream>>>(ctx, wo_bf, (ushort_t*)nullptr, out0,
                                                  hidden, SCALE_DEV, 2048, 5120, 2048);
}